// Round 8
// baseline (955.910 us; speedup 1.0000x reference)
//
#include <hip/hip_runtime.h>
#include <cstdint>

#define LOG2E 1.4426950408889634f

typedef __bf16 bf16x8 __attribute__((ext_vector_type(8)));
typedef float f32x4 __attribute__((ext_vector_type(4)));

#define MFMA16(a,b,c) __builtin_amdgcn_mfma_f32_16x16x32_bf16((a),(b),(c),0,0,0)
#define EXP2(x) __builtin_amdgcn_exp2f(x)

// barrier that orders LDS ops only (no vmcnt drain -> global prefetches stay in flight)
#define LDS_BARRIER() asm volatile("s_waitcnt lgkmcnt(0)\n\ts_barrier" ::: "memory")

// workspace layout (in shorts/bf16 elements)
constexpr size_t OFF_XT = 0;              // [2][4][4096][256]  = 8,388,608
constexpr size_t OFF_QT = 8388608;        // [2][4][4096][32]   = 1,048,576  (pre-scaled by log2e)
constexpr size_t OFF_KT = 9437184;        // [2][4][4096][32]   = 1,048,576
constexpr size_t OFF_V  = 10485760;       // [2][4] fragment-tiled: subtile(c16,j32) -> 1KB lane-linear
constexpr size_t OFF_WQ = 18874368;       // 32*256
constexpr size_t OFF_WK = 18882560;       // 32*256
constexpr size_t OFF_WV = 18890752;       // 256*256
constexpr size_t OFF_WC = 18956288;       // 256*512
constexpr size_t OFF_OP = 19087360;       // partial O: [8 grp][64 it][2 h] x 32KB bf16 images
constexpr size_t OFF_LP = 35864576;       // partial l: [8 grp][64 it][2 h][64] f32
constexpr size_t WS_NEED_BYTES = OFF_LP * 2 + (size_t)8 * 64 * 2 * 64 * 4;  // 71,991,296

static __device__ __forceinline__ unsigned short f2b(float a) {
  return __builtin_bit_cast(unsigned short, (__bf16)a);
}
static __device__ __forceinline__ unsigned pk2(float a, float b) {
  return ((unsigned)f2b(b) << 16) | (unsigned)f2b(a);
}
// sum two packed-bf16 pairs elementwise in f32, scale, repack
static __device__ __forceinline__ unsigned addscale2(unsigned a, unsigned b, float rl) {
  float alo = __builtin_bit_cast(float, a << 16);
  float ahi = __builtin_bit_cast(float, a & 0xffff0000u);
  float blo = __builtin_bit_cast(float, b << 16);
  float bhi = __builtin_bit_cast(float, b & 0xffff0000u);
  return pk2((alo + blo) * rl, (ahi + bhi) * rl);
}

// ---------------------------------------------------------------------------
// Kernel 1: transpose-convert x -> xT[n][c] bf16, and convert weights to bf16
// ---------------------------------------------------------------------------
__global__ __launch_bounds__(256) void prep_kernel(
    const float* __restrict__ x1, const float* __restrict__ x2,
    const float* __restrict__ Wq, const float* __restrict__ Wk,
    const float* __restrict__ Wv, const float* __restrict__ Wc,
    short* __restrict__ ws)
{
  __shared__ float tile[64][65];
  const int tid = threadIdx.x;
  const int blk = blockIdx.x;
  if (blk < 2048) {
    const int nt = blk & 63, ct = (blk >> 6) & 3, b = (blk >> 8) & 3, inp = blk >> 10;
    const float* x = (inp ? x2 : x1) + (size_t)(b * 256 + ct * 64) * 4096 + nt * 64;
#pragma unroll
    for (int p = 0; p < 4; ++p) {
      int r = p * 16 + (tid >> 4);
      float4 v = *(const float4*)(x + (size_t)r * 4096 + (tid & 15) * 4);
      tile[r][(tid & 15) * 4 + 0] = v.x;
      tile[r][(tid & 15) * 4 + 1] = v.y;
      tile[r][(tid & 15) * 4 + 2] = v.z;
      tile[r][(tid & 15) * 4 + 3] = v.w;
    }
    __syncthreads();
    const int n = tid >> 2, c0 = (tid & 3) * 16;
    unsigned u[8];
#pragma unroll
    for (int k = 0; k < 8; ++k)
      u[k] = pk2(tile[c0 + 2 * k][n], tile[c0 + 2 * k + 1][n]);
    short* dst = ws + OFF_XT + (size_t)((inp * 4 + b) * 4096 + nt * 64 + n) * 256 + ct * 64 + c0;
    uint4 s0; s0.x = u[0]; s0.y = u[1]; s0.z = u[2]; s0.w = u[3];
    uint4 s1; s1.x = u[4]; s1.y = u[5]; s1.z = u[6]; s1.w = u[7];
    *(uint4*)(dst) = s0;
    *(uint4*)(dst + 8) = s1;
  } else {
    // weight conversion: [Wq | Wk | Wv | Wc] flat
    int idx = (blk - 2048) * 4096 + tid * 16;
    const float* src; short* dst; int off;
    if (idx < 8192)        { src = Wq; dst = ws + OFF_WQ; off = idx; }
    else if (idx < 16384)  { src = Wk; dst = ws + OFF_WK; off = idx - 8192; }
    else if (idx < 81920)  { src = Wv; dst = ws + OFF_WV; off = idx - 16384; }
    else                   { src = Wc; dst = ws + OFF_WC; off = idx - 81920; }
#pragma unroll
    for (int j = 0; j < 16; ++j) dst[off + j] = (short)f2b(src[off + j]);
  }
}

// ---------------------------------------------------------------------------
// Kernel 2 (merged): blk<256 -> Q/K projections; blk>=256 -> V projection.
// ---------------------------------------------------------------------------
static __device__ __forceinline__ void proj_qk_body(
    short* __restrict__ ws, const float* __restrict__ bq, const float* __restrict__ bk,
    int blk, int tid)
{
  const int lane = tid & 63, wid = tid >> 6;
  const int g = lane >> 4, l15 = lane & 15;
  const int nt = blk & 31, b = (blk >> 5) & 3, inp = blk >> 7;
  const int n0 = nt * 128 + wid * 32;

  const short* xp  = ws + OFF_XT + (size_t)(inp * 4 + b) * (4096 * 256) + (size_t)n0 * 256;
  const short* wqp = ws + OFF_WQ;
  const short* wkp = ws + OFF_WK;
  short* Qt = ws + OFF_QT + (size_t)(inp * 4 + b) * (4096 * 32);
  short* Kt = ws + OFF_KT + (size_t)(inp * 4 + b) * (4096 * 32);

  const f32x4 z4 = {0.f, 0.f, 0.f, 0.f};
  f32x4 aq[2][2], ak[2][2];
#pragma unroll
  for (int i = 0; i < 2; ++i)
#pragma unroll
    for (int j = 0; j < 2; ++j) { aq[i][j] = z4; ak[i][j] = z4; }

#pragma unroll
  for (int ks = 0; ks < 8; ++ks) {
    bf16x8 xa[2];
#pragma unroll
    for (int ns = 0; ns < 2; ++ns)
      xa[ns] = *(const bf16x8*)(xp + (size_t)(ns * 16 + l15) * 256 + ks * 32 + g * 8);
#pragma unroll
    for (int os = 0; os < 2; ++os) {
      bf16x8 wq8 = *(const bf16x8*)(wqp + (size_t)(os * 16 + l15) * 256 + ks * 32 + g * 8);
      bf16x8 wk8 = *(const bf16x8*)(wkp + (size_t)(os * 16 + l15) * 256 + ks * 32 + g * 8);
#pragma unroll
      for (int ns = 0; ns < 2; ++ns) {
        aq[ns][os] = MFMA16(xa[ns], wq8, aq[ns][os]);
        ak[ns][os] = MFMA16(xa[ns], wk8, ak[ns][os]);
      }
    }
  }
  float bqv[2], bkv[2];
#pragma unroll
  for (int os = 0; os < 2; ++os) { bqv[os] = bq[os * 16 + l15]; bkv[os] = bk[os * 16 + l15]; }
#pragma unroll
  for (int ns = 0; ns < 2; ++ns)
#pragma unroll
    for (int os = 0; os < 2; ++os)
#pragma unroll
      for (int r = 0; r < 4; ++r) {
        int n = n0 + ns * 16 + g * 4 + r;
        int o = os * 16 + l15;
        Qt[(size_t)n * 32 + o] = (short)f2b((aq[ns][os][r] + bqv[os]) * LOG2E);
        Kt[(size_t)n * 32 + o] = (short)f2b(ak[ns][os][r] + bkv[os]);
      }
}

static __device__ __forceinline__ void proj_v_body(
    short* __restrict__ ws, const float* __restrict__ bv, char* vl, int blk, int tid)
{
  const int lane = tid & 63, wid = tid >> 6;
  const int g = lane >> 4, l15 = lane & 15;
  const int nt = blk & 63, b = (blk >> 6) & 3, inp = blk >> 8;
  const int n0 = nt * 64;

  const short* xp  = ws + OFF_XT + (size_t)(inp * 4 + b) * (4096 * 256) + (size_t)n0 * 256;
  const short* wvp = ws + OFF_WV;
  short* Vp = ws + OFF_V + (size_t)(inp * 4 + b) * (256 * 4096);

  const f32x4 z4 = {0.f, 0.f, 0.f, 0.f};
  f32x4 acc[4][4];
#pragma unroll
  for (int i = 0; i < 4; ++i)
#pragma unroll
    for (int j = 0; j < 4; ++j) acc[i][j] = z4;

#pragma unroll
  for (int ks = 0; ks < 8; ++ks) {
    bf16x8 xa[4];
#pragma unroll
    for (int ns = 0; ns < 4; ++ns)
      xa[ns] = *(const bf16x8*)(xp + (size_t)(ns * 16 + l15) * 256 + ks * 32 + g * 8);
#pragma unroll
    for (int os = 0; os < 4; ++os) {
      bf16x8 wv8 = *(const bf16x8*)(wvp + (size_t)(wid * 64 + os * 16 + l15) * 256 + ks * 32 + g * 8);
#pragma unroll
      for (int ns = 0; ns < 4; ++ns)
        acc[os][ns] = MFMA16(wv8, xa[ns], acc[os][ns]);
    }
  }
  float bvv[4][4];
#pragma unroll
  for (int os = 0; os < 4; ++os)
#pragma unroll
    for (int r = 0; r < 4; ++r) bvv[os][r] = bv[wid * 64 + os * 16 + g * 4 + r];

  char* myl = vl + wid * 8192;
#pragma unroll
  for (int os = 0; os < 4; ++os)
#pragma unroll
    for (int ns = 0; ns < 4; ++ns)
#pragma unroll
      for (int r = 0; r < 4; ++r) {
        int o_loc = os * 16 + g * 4 + r;
        int n_loc = ns * 16 + l15;
        *(short*)(myl + o_loc * 128 + ((n_loc * 2) ^ ((o_loc & 7) << 4))) =
            (short)f2b(acc[os][ns][r] + bvv[os][r]);
      }
  // wave-local fragment readback (same wave -> lgkmcnt ordering suffices)
#pragma unroll
  for (int sc = 0; sc < 4; ++sc)
#pragma unroll
    for (int sj = 0; sj < 2; ++sj) {
      int c_loc = sc * 16 + l15;
      bf16x8 row = *(const bf16x8*)(myl + c_loc * 128 +
                                    (((unsigned)(sj * 64 + g * 16)) ^ ((c_loc & 7) << 4)));
      size_t c16 = (size_t)(wid * 4 + sc);
      size_t j32 = (size_t)(nt * 2 + sj);
      *(bf16x8*)(Vp + (c16 * 128 + j32) * 512 + lane * 8) = row;
    }
}

__global__ __launch_bounds__(256) void proj_kernel(
    short* __restrict__ ws, const float* __restrict__ bq,
    const float* __restrict__ bk, const float* __restrict__ bv)
{
  __shared__ __align__(16) char vl[32768];
  const int tid = threadIdx.x, blk = blockIdx.x;
  if (blk < 256) proj_qk_body(ws, bq, bk, blk, tid);
  else           proj_v_body(ws, bv, vl, blk - 256, tid);
}

// shared loop body for the attention K-loop (identical in both attn kernels)
#define ATTN_BODY(TC, CUR, NXT, PBR, PBW, DO_S, PREFK, PREFV)                            \
  do {                                                                                   \
    f32x4 st[4];                                                                         \
    if (DO_S) {                                                                          \
      _Pragma("unroll")                                                                  \
      for (int jt = 0; jt < 4; ++jt) st[jt] = MFMA16(kf[CUR][jt], qf, z4);               \
    }                                                                                    \
    if (PREFK) {                                                                         \
      _Pragma("unroll")                                                                  \
      for (int jt = 0; jt < 4; ++jt)                                                     \
        kf[NXT][jt] = *(const bf16x8*)(Kb + (size_t)(((TC) + 2) * 64 + jt * 16 + l15) * 32 + g * 8); \
    }                                                                                    \
    if (PREFV) {                                                                         \
      _Pragma("unroll")                                                                  \
      for (int ks = 0; ks < 2; ++ks)                                                     \
        _Pragma("unroll")                                                                \
        for (int cs = 0; cs < 4; ++cs)                                                   \
          va[NXT][ks][cs] = *(const bf16x8*)(Vb + ((size_t)(wid * 4 + cs) * 128 +        \
                                                   (size_t)((TC) + 1) * 2 + ks) * 512 + lane * 8); \
    }                                                                                    \
    __builtin_amdgcn_s_setprio(1);                                                       \
    {                                                                                    \
      const char* Pl = sm + (PBR) * 8192;                                                \
      _Pragma("unroll")                                                                  \
      for (int ks = 0; ks < 2; ++ks)                                                     \
        _Pragma("unroll")                                                                \
        for (int it = 0; it < 4; ++it) {                                                 \
          int i = it * 16 + l15;                                                         \
          bf16x8 pb = *(const bf16x8*)(Pl + i * 128 +                                    \
                                       (((unsigned)(ks * 64 + g * 16)) ^ ((i & 7) << 4))); \
          _Pragma("unroll")                                                              \
          for (int cs = 0; cs < 4; ++cs)                                                 \
            oc[cs][it] = MFMA16(va[CUR][ks][cs], pb, oc[cs][it]);                        \
        }                                                                                \
    }                                                                                    \
    __builtin_amdgcn_s_setprio(0);                                                       \
    if (DO_S) {                                                                          \
      char* Pw = sm + (PBW) * 8192;                                                      \
      _Pragma("unroll")                                                                  \
      for (int jt = 0; jt < 4; ++jt) {                                                   \
        _Pragma("unroll")                                                                \
        for (int r = 0; r < 4; ++r) {                                                    \
          float p = EXP2(st[jt][r]);                                                     \
          st[jt][r] = p;                                                                 \
          l_run += p;                                                                    \
        }                                                                                \
        unsigned long long u =                                                           \
            ((unsigned long long)pk2(st[jt][2], st[jt][3]) << 32) | pk2(st[jt][0], st[jt][1]); \
        *(unsigned long long*)(Pw + irow * 128 + (((unsigned)(jt * 32 + g * 8)) ^ sw)) = u; \
      }                                                                                  \
    }                                                                                    \
    LDS_BARRIER();                                                                       \
  } while (0)

// ---------------------------------------------------------------------------
// Kernel 3a: attention main loop over a j-HALF (grid 1024 -> 4 blocks/CU,
// 16 waves/CU). Stages unnormalized O^T (bf16, swizzled 32KB image) +
// l-partials to workspace. bid = grp*128 + itile*2 + h (XCD-swizzled).
// ---------------------------------------------------------------------------
__global__ __launch_bounds__(256, 4) void attn_main_kernel(short* __restrict__ ws)
{
  const int tid = threadIdx.x, lane = tid & 63, wid = tid >> 6;
  const int g = lane >> 4, l15 = lane & 15;
  const int bid = ((blockIdx.x & 7) << 7) | (blockIdx.x >> 3);
  const int h = bid & 1, itile = (bid >> 1) & 63, grp = bid >> 7;
  const int b = grp & 3, br = grp >> 2;
  const int i0 = itile * 64, t0 = h * 32;

  __shared__ __align__(16) char sm[33024];
  float* l_l = (float*)(sm + 32768);   // 64 floats

  const short* Qb = ws + OFF_QT + (size_t)(br * 4 + b) * (4096 * 32);
  const short* Kb = ws + OFF_KT + (size_t)(br * 4 + b) * (4096 * 32);
  const short* Vb = ws + OFF_V  + (size_t)((1 - br) * 4 + b) * (256 * 4096);

  const f32x4 z4 = {0.f, 0.f, 0.f, 0.f};
  const int irow = wid * 16 + l15;
  const unsigned sw = (unsigned)((irow & 7) << 4);

  bf16x8 qf = *(const bf16x8*)(Qb + (size_t)(i0 + wid * 16 + l15) * 32 + g * 8);

  f32x4 oc[4][4];
#pragma unroll
  for (int i = 0; i < 4; ++i)
#pragma unroll
    for (int j = 0; j < 4; ++j) oc[i][j] = z4;
  float l_run = 0.f;

  // prologue: S(t0) -> P buf0; prefetch kf<-K(t0+1), va<-V(t0)
  {
    bf16x8 kt[4];
#pragma unroll
    for (int jt = 0; jt < 4; ++jt)
      kt[jt] = *(const bf16x8*)(Kb + (size_t)(t0 * 64 + jt * 16 + l15) * 32 + g * 8);
    f32x4 s0[4];
#pragma unroll
    for (int jt = 0; jt < 4; ++jt) s0[jt] = MFMA16(kt[jt], qf, z4);
#pragma unroll
    for (int jt = 0; jt < 4; ++jt) {
#pragma unroll
      for (int r = 0; r < 4; ++r) {
        float p = EXP2(s0[jt][r]);
        s0[jt][r] = p;
        l_run += p;
      }
      unsigned long long u =
          ((unsigned long long)pk2(s0[jt][2], s0[jt][3]) << 32) | pk2(s0[jt][0], s0[jt][1]);
      *(unsigned long long*)(sm + irow * 128 + (((unsigned)(jt * 32 + g * 8)) ^ sw)) = u;
    }
  }

  bf16x8 kf[2][4], va[2][2][4];
#pragma unroll
  for (int jt = 0; jt < 4; ++jt)
    kf[0][jt] = *(const bf16x8*)(Kb + (size_t)((t0 + 1) * 64 + jt * 16 + l15) * 32 + g * 8);
#pragma unroll
  for (int ks = 0; ks < 2; ++ks)
#pragma unroll
    for (int cs = 0; cs < 4; ++cs)
      va[0][ks][cs] = *(const bf16x8*)(Vb + ((size_t)(wid * 4 + cs) * 128 + (size_t)t0 * 2 + ks) * 512 + lane * 8);

  LDS_BARRIER();

  for (int t = t0; t < t0 + 30; t += 2) {
    ATTN_BODY(t, 0, 1, 0, 1, 1, 1, 1);
    ATTN_BODY(t + 1, 1, 0, 1, 0, 1, 1, 1);
  }
  ATTN_BODY(t0 + 30, 0, 1, 0, 1, 1, 0, 1);   // S(t0+31), PV(t0+30), fetch V(t0+31)
  ATTN_BODY(t0 + 31, 1, 0, 1, 0, 0, 0, 0);   // PV(t0+31) only

  // deferred softmax-denominator partial (this half)
  l_run += __shfl_xor(l_run, 16);
  l_run += __shfl_xor(l_run, 32);
  if (g == 0) l_l[irow] = l_run;

  // stage UNNORMALIZED O^T bf16 into the swizzled [i][c] image
#pragma unroll
  for (int cs = 0; cs < 4; ++cs)
#pragma unroll
    for (int it = 0; it < 4; ++it) {
      f32x4 v = oc[cs][it];
      int i = it * 16 + l15;
      unsigned byte = (unsigned)(i * 512) +
                      (((unsigned)((wid * 64 + cs * 16 + g * 4) * 2)) ^ ((i & 7) << 4));
      unsigned long long u = ((unsigned long long)pk2(v[2], v[3]) << 32) | pk2(v[0], v[1]);
      *(unsigned long long*)(sm + byte) = u;
    }
  __syncthreads();

  // coalesced copy of the 32KB image + l partials to workspace
  char* OpH = (char*)(ws + OFF_OP) + (((size_t)(grp * 64 + itile)) * 2 + h) * 32768;
#pragma unroll
  for (int k = 0; k < 8; ++k)
    *(uint4*)(OpH + tid * 128 + k * 16) = *(const uint4*)(sm + tid * 128 + k * 16);
  if (tid < 64) {
    float* Lp = (float*)(ws + OFF_LP);
    Lp[(size_t)(grp * 64 + itile) * 128 + h * 64 + tid] = l_l[tid];
  }
}

// ---------------------------------------------------------------------------
// Kernel 3b: combine partials -> normalize -> Wc GEMM + abs-sum.
// grid 512: bid = grp*64 + itile (XCD-swizzled)
// ---------------------------------------------------------------------------
__global__ __launch_bounds__(256, 2) void combine_kernel(
    short* __restrict__ ws, const float* __restrict__ bc, float* __restrict__ out)
{
  const int tid = threadIdx.x, lane = tid & 63, wid = tid >> 6;
  const int g = lane >> 4, l15 = lane & 15;
  const int bid = ((blockIdx.x & 7) << 6) | (blockIdx.x >> 3);
  const int itile = bid & 63, grp = bid >> 6;
  const int b = grp & 3, br = grp >> 2;
  const int i0 = itile * 64;

  __shared__ __align__(16) char sm[34304];
  float* l_l  = (float*)(sm + 32768);   // 128 floats: l0[64], l1[64]
  float* part = (float*)(sm + 33280);   // 256 floats

  const short* xb  = ws + OFF_XT + (size_t)b * (4096 * 256);   // x1 for both branches
  const short* Wcb = ws + OFF_WC;
  const char*  op0 = (const char*)(ws + OFF_OP) + ((size_t)(grp * 64 + itile) * 2) * 32768;
  const char*  op1 = op0 + 32768;
  const float* Lp  = (const float*)(ws + OFF_LP) + (size_t)(grp * 64 + itile) * 128;

  if (tid < 128) l_l[tid] = Lp[tid];
  __syncthreads();

  // sum halves + normalize, rebuild the swizzled staging image
#pragma unroll
  for (int k = 0; k < 8; ++k) {
    int addr = tid * 128 + k * 16;
    uint4 a  = *(const uint4*)(op0 + addr);
    uint4 b2 = *(const uint4*)(op1 + addr);
    int i = addr >> 9;
    float rl = 1.f / (l_l[i] + l_l[64 + i]);
    uint4 o;
    o.x = addscale2(a.x, b2.x, rl);
    o.y = addscale2(a.y, b2.y, rl);
    o.z = addscale2(a.z, b2.z, rl);
    o.w = addscale2(a.w, b2.w, rl);
    *(uint4*)(sm + addr) = o;
  }
  __syncthreads();

  const f32x4 z4 = {0.f, 0.f, 0.f, 0.f};
  f32x4 cc[4][4];
#pragma unroll
  for (int i = 0; i < 4; ++i)
#pragma unroll
    for (int j = 0; j < 4; ++j) cc[i][j] = z4;

#pragma unroll
  for (int ks = 0; ks < 16; ++ks) {
    bf16x8 bfr[4];
#pragma unroll
    for (int ns = 0; ns < 4; ++ns) {
      int n = ns * 16 + l15;
      if (ks < 8)
        bfr[ns] = *(const bf16x8*)(xb + (size_t)(i0 + n) * 256 + ks * 32 + g * 8);
      else
        bfr[ns] = *(const bf16x8*)(sm + n * 512 +
                                   (((unsigned)((ks - 8) * 64 + g * 16)) ^ ((n & 7) << 4)));
    }
#pragma unroll
    for (int os = 0; os < 4; ++os) {
      bf16x8 af = *(const bf16x8*)(Wcb + (size_t)(wid * 64 + os * 16 + l15) * 512 + ks * 32 + g * 8);
#pragma unroll
      for (int ns = 0; ns < 4; ++ns)
        cc[os][ns] = MFMA16(af, bfr[ns], cc[os][ns]);
    }
  }
  float bcv[4][4];
#pragma unroll
  for (int os = 0; os < 4; ++os)
#pragma unroll
    for (int r = 0; r < 4; ++r) bcv[os][r] = bc[wid * 64 + os * 16 + g * 4 + r];

#pragma unroll
  for (int ns = 0; ns < 4; ++ns) {
    float tsum = 0.f;
#pragma unroll
    for (int os = 0; os < 4; ++os)
#pragma unroll
      for (int r = 0; r < 4; ++r)
        tsum += fabsf(cc[os][ns][r] + bcv[os][r]);
    tsum += __shfl_xor(tsum, 16);
    tsum += __shfl_xor(tsum, 32);
    if (g == 0) part[wid * 64 + ns * 16 + l15] = tsum;
  }
  __syncthreads();
  if (tid < 64) {
    float s = part[tid] + part[64 + tid] + part[128 + tid] + part[192 + tid];
    out[(size_t)br * 16384 + b * 4096 + i0 + tid] = s;
  }
}

// ---------------------------------------------------------------------------
// Kernel 3 (fallback, round-7 fused version): used when ws is too small
// ---------------------------------------------------------------------------
__global__ __launch_bounds__(256, 2) void attn_kernel(
    short* __restrict__ ws, const float* __restrict__ bc, float* __restrict__ out)
{
  const int tid = threadIdx.x, lane = tid & 63, wid = tid >> 6;
  const int g = lane >> 4, l15 = lane & 15;
  const int bid = ((blockIdx.x & 7) << 6) | (blockIdx.x >> 3);
  const int itile = bid & 63, b = (bid >> 6) & 3, br = bid >> 8;
  const int i0 = itile * 64;

  __shared__ __align__(16) char sm[34048];
  float* l_l  = (float*)(sm + 32768);   // 64 floats
  float* part = (float*)(sm + 33024);   // 256 floats

  const short* Qb  = ws + OFF_QT + (size_t)(br * 4 + b) * (4096 * 32);
  const short* Kb  = ws + OFF_KT + (size_t)(br * 4 + b) * (4096 * 32);
  const short* Vb  = ws + OFF_V  + (size_t)((1 - br) * 4 + b) * (256 * 4096);
  const short* xb  = ws + OFF_XT + (size_t)b * (4096 * 256);
  const short* Wcb = ws + OFF_WC;

  const f32x4 z4 = {0.f, 0.f, 0.f, 0.f};
  const int irow = wid * 16 + l15;
  const unsigned sw = (unsigned)((irow & 7) << 4);

  bf16x8 qf = *(const bf16x8*)(Qb + (size_t)(i0 + wid * 16 + l15) * 32 + g * 8);

  f32x4 oc[4][4];
#pragma unroll
  for (int i = 0; i < 4; ++i)
#pragma unroll
    for (int j = 0; j < 4; ++j) oc[i][j] = z4;
  float l_run = 0.f;

  {
    bf16x8 kt[4];
#pragma unroll
    for (int jt = 0; jt < 4; ++jt)
      kt[jt] = *(const bf16x8*)(Kb + (size_t)(jt * 16 + l15) * 32 + g * 8);
    f32x4 s0[4];
#pragma unroll
    for (int jt = 0; jt < 4; ++jt) s0[jt] = MFMA16(kt[jt], qf, z4);
#pragma unroll
    for (int jt = 0; jt < 4; ++jt) {
#pragma unroll
      for (int r = 0; r < 4; ++r) {
        float p = EXP2(s0[jt][r]);
        s0[jt][r] = p;
        l_run += p;
      }
      unsigned long long u =
          ((unsigned long long)pk2(s0[jt][2], s0[jt][3]) << 32) | pk2(s0[jt][0], s0[jt][1]);
      *(unsigned long long*)(sm + irow * 128 + (((unsigned)(jt * 32 + g * 8)) ^ sw)) = u;
    }
  }

  bf16x8 kf[2][4], va[2][2][4];
#pragma unroll
  for (int jt = 0; jt < 4; ++jt)
    kf[0][jt] = *(const bf16x8*)(Kb + (size_t)(64 + jt * 16 + l15) * 32 + g * 8);
#pragma unroll
  for (int ks = 0; ks < 2; ++ks)
#pragma unroll
    for (int cs = 0; cs < 4; ++cs)
      va[0][ks][cs] = *(const bf16x8*)(Vb + ((size_t)(wid * 4 + cs) * 128 + ks) * 512 + lane * 8);

  LDS_BARRIER();

  for (int t = 0; t < 62; t += 2) {
    ATTN_BODY(t, 0, 1, 0, 1, 1, 1, 1);
    ATTN_BODY(t + 1, 1, 0, 1, 0, 1, 1, 1);
  }
  ATTN_BODY(62, 0, 1, 0, 1, 1, 0, 1);
  ATTN_BODY(63, 1, 0, 1, 0, 0, 0, 0);

  l_run += __shfl_xor(l_run, 16);
  l_run += __shfl_xor(l_run, 32);

  if (g == 0) l_l[irow] = l_run;
  __syncthreads();
  float rl[4];
#pragma unroll
  for (int it = 0; it < 4; ++it) rl[it] = 1.f / l_l[it * 16 + l15];

#pragma unroll
  for (int cs = 0; cs < 4; ++cs)
#pragma unroll
    for (int it = 0; it < 4; ++it) {
      f32x4 v = oc[cs][it];
      v *= rl[it];
      int i = it * 16 + l15;
      unsigned byte = (unsigned)(i * 512) +
                      (((unsigned)((wid * 64 + cs * 16 + g * 4) * 2)) ^ ((i & 7) << 4));
      unsigned long long u = ((unsigned long long)pk2(v[2], v[3]) << 32) | pk2(v[0], v[1]);
      *(unsigned long long*)(sm + byte) = u;
    }
  __syncthreads();

  f32x4 cc[4][4];
#pragma unroll
  for (int i = 0; i < 4; ++i)
#pragma unroll
    for (int j = 0; j < 4; ++j) cc[i][j] = z4;

#pragma unroll
  for (int ks = 0; ks < 16; ++ks) {
    bf16x8 bfr[4];
#pragma unroll
    for (int ns = 0; ns < 4; ++ns) {
      int n = ns * 16 + l15;
      if (ks < 8)
        bfr[ns] = *(const bf16x8*)(xb + (size_t)(i0 + n) * 256 + ks * 32 + g * 8);
      else
        bfr[ns] = *(const bf16x8*)(sm + n * 512 +
                                   (((unsigned)((ks - 8) * 64 + g * 16)) ^ ((n & 7) << 4)));
    }
#pragma unroll
    for (int os = 0; os < 4; ++os) {
      bf16x8 af = *(const bf16x8*)(Wcb + (size_t)(wid * 64 + os * 16 + l15) * 512 + ks * 32 + g * 8);
#pragma unroll
      for (int ns = 0; ns < 4; ++ns)
        cc[os][ns] = MFMA16(af, bfr[ns], cc[os][ns]);
    }
  }
  float bcv[4][4];
#pragma unroll
  for (int os = 0; os < 4; ++os)
#pragma unroll
    for (int r = 0; r < 4; ++r) bcv[os][r] = bc[wid * 64 + os * 16 + g * 4 + r];

#pragma unroll
  for (int ns = 0; ns < 4; ++ns) {
    float tsum = 0.f;
#pragma unroll
    for (int os = 0; os < 4; ++os)
#pragma unroll
      for (int r = 0; r < 4; ++r)
        tsum += fabsf(cc[os][ns][r] + bcv[os][r]);
    tsum += __shfl_xor(tsum, 16);
    tsum += __shfl_xor(tsum, 32);
    if (g == 0) part[wid * 64 + ns * 16 + l15] = tsum;
  }
  __syncthreads();
  if (tid < 64) {
    float s = part[tid] + part[64 + tid] + part[128 + tid] + part[192 + tid];
    out[(size_t)br * 16384 + b * 4096 + i0 + tid] = s;
  }
}

// ---------------------------------------------------------------------------
extern "C" void kernel_launch(void* const* d_in, const int* in_sizes, int n_in,
                              void* d_out, int out_size, void* d_ws, size_t ws_size,
                              hipStream_t stream) {
  const float* x1 = (const float*)d_in[0];
  const float* x2 = (const float*)d_in[1];
  const float* Wq = (const float*)d_in[2];
  const float* bq = (const float*)d_in[3];
  const float* Wk = (const float*)d_in[4];
  const float* bk = (const float*)d_in[5];
  const float* Wv = (const float*)d_in[6];
  const float* bv = (const float*)d_in[7];
  const float* Wc = (const float*)d_in[8];
  const float* bc = (const float*)d_in[9];
  short* ws = (short*)d_ws;
  float* out = (float*)d_out;

  prep_kernel<<<2100, 256, 0, stream>>>(x1, x2, Wq, Wk, Wv, Wc, ws);
  proj_kernel<<<768, 256, 0, stream>>>(ws, bq, bk, bv);
  if (ws_size >= WS_NEED_BYTES) {
    attn_main_kernel<<<1024, 256, 0, stream>>>(ws);
    combine_kernel<<<512, 256, 0, stream>>>(ws, bc, out);
  } else {
    attn_kernel<<<512, 256, 0, stream>>>(ws, bc, out);
  }
}

// Round 9
// 156.958 us; speedup vs baseline: 6.0902x; 6.0902x over previous
//
#include <hip/hip_runtime.h>
#include <cstdint>

#define LOG2E 1.4426950408889634f

typedef __bf16 bf16x8 __attribute__((ext_vector_type(8)));
typedef float f32x4 __attribute__((ext_vector_type(4)));

#define MFMA16(a,b,c) __builtin_amdgcn_mfma_f32_16x16x32_bf16((a),(b),(c),0,0,0)
#define EXP2(x) __builtin_amdgcn_exp2f(x)

// barrier that orders LDS ops only (no vmcnt drain -> global prefetches stay in flight)
#define LDS_BARRIER() asm volatile("s_waitcnt lgkmcnt(0)\n\ts_barrier" ::: "memory")

// workspace layout (in shorts/bf16 elements)
constexpr size_t OFF_XT = 0;              // [2][4][4096][256]  = 8,388,608
constexpr size_t OFF_QT = 8388608;        // [2][4][4096][32]   = 1,048,576  (pre-scaled by log2e)
constexpr size_t OFF_KT = 9437184;        // [2][4][4096][32]   = 1,048,576
constexpr size_t OFF_V  = 10485760;       // [2][4] fragment-tiled: subtile(c16,j32) -> 1KB lane-linear
constexpr size_t OFF_WQ = 18874368;       // 32*256
constexpr size_t OFF_WK = 18882560;       // 32*256
constexpr size_t OFF_WV = 18890752;       // 256*256
constexpr size_t OFF_WC = 18956288;       // 256*512
constexpr size_t OFF_OP = 19087360;       // partial O: [8 grp][64 it][2 h] x 32KB bf16 images
constexpr size_t OFF_LP = 35864576;       // partial l: [8 grp][64 it][2 h][64] f32
constexpr size_t WS_NEED_BYTES = OFF_LP * 2 + (size_t)8 * 64 * 2 * 64 * 4;  // 71,991,296

static __device__ __forceinline__ unsigned short f2b(float a) {
  return __builtin_bit_cast(unsigned short, (__bf16)a);
}
static __device__ __forceinline__ unsigned pk2(float a, float b) {
  return ((unsigned)f2b(b) << 16) | (unsigned)f2b(a);
}
// sum two packed-bf16 pairs elementwise in f32, scale, repack
static __device__ __forceinline__ unsigned addscale2(unsigned a, unsigned b, float rl) {
  float alo = __builtin_bit_cast(float, a << 16);
  float ahi = __builtin_bit_cast(float, a & 0xffff0000u);
  float blo = __builtin_bit_cast(float, b << 16);
  float bhi = __builtin_bit_cast(float, b & 0xffff0000u);
  return pk2((alo + blo) * rl, (ahi + bhi) * rl);
}

// ---------------------------------------------------------------------------
// Kernel 1: transpose-convert x -> xT[n][c] bf16, and convert weights to bf16
// ---------------------------------------------------------------------------
__global__ __launch_bounds__(256) void prep_kernel(
    const float* __restrict__ x1, const float* __restrict__ x2,
    const float* __restrict__ Wq, const float* __restrict__ Wk,
    const float* __restrict__ Wv, const float* __restrict__ Wc,
    short* __restrict__ ws)
{
  __shared__ float tile[64][65];
  const int tid = threadIdx.x;
  const int blk = blockIdx.x;
  if (blk < 2048) {
    const int nt = blk & 63, ct = (blk >> 6) & 3, b = (blk >> 8) & 3, inp = blk >> 10;
    const float* x = (inp ? x2 : x1) + (size_t)(b * 256 + ct * 64) * 4096 + nt * 64;
#pragma unroll
    for (int p = 0; p < 4; ++p) {
      int r = p * 16 + (tid >> 4);
      float4 v = *(const float4*)(x + (size_t)r * 4096 + (tid & 15) * 4);
      tile[r][(tid & 15) * 4 + 0] = v.x;
      tile[r][(tid & 15) * 4 + 1] = v.y;
      tile[r][(tid & 15) * 4 + 2] = v.z;
      tile[r][(tid & 15) * 4 + 3] = v.w;
    }
    __syncthreads();
    const int n = tid >> 2, c0 = (tid & 3) * 16;
    unsigned u[8];
#pragma unroll
    for (int k = 0; k < 8; ++k)
      u[k] = pk2(tile[c0 + 2 * k][n], tile[c0 + 2 * k + 1][n]);
    short* dst = ws + OFF_XT + (size_t)((inp * 4 + b) * 4096 + nt * 64 + n) * 256 + ct * 64 + c0;
    uint4 s0; s0.x = u[0]; s0.y = u[1]; s0.z = u[2]; s0.w = u[3];
    uint4 s1; s1.x = u[4]; s1.y = u[5]; s1.z = u[6]; s1.w = u[7];
    *(uint4*)(dst) = s0;
    *(uint4*)(dst + 8) = s1;
  } else {
    // weight conversion: [Wq | Wk | Wv | Wc] flat
    int idx = (blk - 2048) * 4096 + tid * 16;
    const float* src; short* dst; int off;
    if (idx < 8192)        { src = Wq; dst = ws + OFF_WQ; off = idx; }
    else if (idx < 16384)  { src = Wk; dst = ws + OFF_WK; off = idx - 8192; }
    else if (idx < 81920)  { src = Wv; dst = ws + OFF_WV; off = idx - 16384; }
    else                   { src = Wc; dst = ws + OFF_WC; off = idx - 81920; }
#pragma unroll
    for (int j = 0; j < 16; ++j) dst[off + j] = (short)f2b(src[off + j]);
  }
}

// ---------------------------------------------------------------------------
// Kernel 2 (merged): blk<256 -> Q/K projections; blk>=256 -> V projection.
// ---------------------------------------------------------------------------
static __device__ __forceinline__ void proj_qk_body(
    short* __restrict__ ws, const float* __restrict__ bq, const float* __restrict__ bk,
    int blk, int tid)
{
  const int lane = tid & 63, wid = tid >> 6;
  const int g = lane >> 4, l15 = lane & 15;
  const int nt = blk & 31, b = (blk >> 5) & 3, inp = blk >> 7;
  const int n0 = nt * 128 + wid * 32;

  const short* xp  = ws + OFF_XT + (size_t)(inp * 4 + b) * (4096 * 256) + (size_t)n0 * 256;
  const short* wqp = ws + OFF_WQ;
  const short* wkp = ws + OFF_WK;
  short* Qt = ws + OFF_QT + (size_t)(inp * 4 + b) * (4096 * 32);
  short* Kt = ws + OFF_KT + (size_t)(inp * 4 + b) * (4096 * 32);

  const f32x4 z4 = {0.f, 0.f, 0.f, 0.f};
  f32x4 aq[2][2], ak[2][2];
#pragma unroll
  for (int i = 0; i < 2; ++i)
#pragma unroll
    for (int j = 0; j < 2; ++j) { aq[i][j] = z4; ak[i][j] = z4; }

#pragma unroll
  for (int ks = 0; ks < 8; ++ks) {
    bf16x8 xa[2];
#pragma unroll
    for (int ns = 0; ns < 2; ++ns)
      xa[ns] = *(const bf16x8*)(xp + (size_t)(ns * 16 + l15) * 256 + ks * 32 + g * 8);
#pragma unroll
    for (int os = 0; os < 2; ++os) {
      bf16x8 wq8 = *(const bf16x8*)(wqp + (size_t)(os * 16 + l15) * 256 + ks * 32 + g * 8);
      bf16x8 wk8 = *(const bf16x8*)(wkp + (size_t)(os * 16 + l15) * 256 + ks * 32 + g * 8);
#pragma unroll
      for (int ns = 0; ns < 2; ++ns) {
        aq[ns][os] = MFMA16(xa[ns], wq8, aq[ns][os]);
        ak[ns][os] = MFMA16(xa[ns], wk8, ak[ns][os]);
      }
    }
  }
  float bqv[2], bkv[2];
#pragma unroll
  for (int os = 0; os < 2; ++os) { bqv[os] = bq[os * 16 + l15]; bkv[os] = bk[os * 16 + l15]; }
#pragma unroll
  for (int ns = 0; ns < 2; ++ns)
#pragma unroll
    for (int os = 0; os < 2; ++os)
#pragma unroll
      for (int r = 0; r < 4; ++r) {
        int n = n0 + ns * 16 + g * 4 + r;
        int o = os * 16 + l15;
        Qt[(size_t)n * 32 + o] = (short)f2b((aq[ns][os][r] + bqv[os]) * LOG2E);
        Kt[(size_t)n * 32 + o] = (short)f2b(ak[ns][os][r] + bkv[os]);
      }
}

static __device__ __forceinline__ void proj_v_body(
    short* __restrict__ ws, const float* __restrict__ bv, char* vl, int blk, int tid)
{
  const int lane = tid & 63, wid = tid >> 6;
  const int g = lane >> 4, l15 = lane & 15;
  const int nt = blk & 63, b = (blk >> 6) & 3, inp = blk >> 8;
  const int n0 = nt * 64;

  const short* xp  = ws + OFF_XT + (size_t)(inp * 4 + b) * (4096 * 256) + (size_t)n0 * 256;
  const short* wvp = ws + OFF_WV;
  short* Vp = ws + OFF_V + (size_t)(inp * 4 + b) * (256 * 4096);

  const f32x4 z4 = {0.f, 0.f, 0.f, 0.f};
  f32x4 acc[4][4];
#pragma unroll
  for (int i = 0; i < 4; ++i)
#pragma unroll
    for (int j = 0; j < 4; ++j) acc[i][j] = z4;

#pragma unroll
  for (int ks = 0; ks < 8; ++ks) {
    bf16x8 xa[4];
#pragma unroll
    for (int ns = 0; ns < 4; ++ns)
      xa[ns] = *(const bf16x8*)(xp + (size_t)(ns * 16 + l15) * 256 + ks * 32 + g * 8);
#pragma unroll
    for (int os = 0; os < 4; ++os) {
      bf16x8 wv8 = *(const bf16x8*)(wvp + (size_t)(wid * 64 + os * 16 + l15) * 256 + ks * 32 + g * 8);
#pragma unroll
      for (int ns = 0; ns < 4; ++ns)
        acc[os][ns] = MFMA16(wv8, xa[ns], acc[os][ns]);
    }
  }
  float bvv[4][4];
#pragma unroll
  for (int os = 0; os < 4; ++os)
#pragma unroll
    for (int r = 0; r < 4; ++r) bvv[os][r] = bv[wid * 64 + os * 16 + g * 4 + r];

  char* myl = vl + wid * 8192;
#pragma unroll
  for (int os = 0; os < 4; ++os)
#pragma unroll
    for (int ns = 0; ns < 4; ++ns)
#pragma unroll
      for (int r = 0; r < 4; ++r) {
        int o_loc = os * 16 + g * 4 + r;
        int n_loc = ns * 16 + l15;
        *(short*)(myl + o_loc * 128 + ((n_loc * 2) ^ ((o_loc & 7) << 4))) =
            (short)f2b(acc[os][ns][r] + bvv[os][r]);
      }
  // wave-local fragment readback (same wave -> lgkmcnt ordering suffices)
#pragma unroll
  for (int sc = 0; sc < 4; ++sc)
#pragma unroll
    for (int sj = 0; sj < 2; ++sj) {
      int c_loc = sc * 16 + l15;
      bf16x8 row = *(const bf16x8*)(myl + c_loc * 128 +
                                    (((unsigned)(sj * 64 + g * 16)) ^ ((c_loc & 7) << 4)));
      size_t c16 = (size_t)(wid * 4 + sc);
      size_t j32 = (size_t)(nt * 2 + sj);
      *(bf16x8*)(Vp + (c16 * 128 + j32) * 512 + lane * 8) = row;
    }
}

__global__ __launch_bounds__(256) void proj_kernel(
    short* __restrict__ ws, const float* __restrict__ bq,
    const float* __restrict__ bk, const float* __restrict__ bv)
{
  __shared__ __align__(16) char vl[32768];
  const int tid = threadIdx.x, blk = blockIdx.x;
  if (blk < 256) proj_qk_body(ws, bq, bk, blk, tid);
  else           proj_v_body(ws, bv, vl, blk - 256, tid);
}

// shared loop body for the attention K-loop (identical in both attn kernels)
#define ATTN_BODY(TC, CUR, NXT, PBR, PBW, DO_S, PREFK, PREFV)                            \
  do {                                                                                   \
    f32x4 st[4];                                                                         \
    if (DO_S) {                                                                          \
      _Pragma("unroll")                                                                  \
      for (int jt = 0; jt < 4; ++jt) st[jt] = MFMA16(kf[CUR][jt], qf, z4);               \
    }                                                                                    \
    if (PREFK) {                                                                         \
      _Pragma("unroll")                                                                  \
      for (int jt = 0; jt < 4; ++jt)                                                     \
        kf[NXT][jt] = *(const bf16x8*)(Kb + (size_t)(((TC) + 2) * 64 + jt * 16 + l15) * 32 + g * 8); \
    }                                                                                    \
    if (PREFV) {                                                                         \
      _Pragma("unroll")                                                                  \
      for (int ks = 0; ks < 2; ++ks)                                                     \
        _Pragma("unroll")                                                                \
        for (int cs = 0; cs < 4; ++cs)                                                   \
          va[NXT][ks][cs] = *(const bf16x8*)(Vb + ((size_t)(wid * 4 + cs) * 128 +        \
                                                   (size_t)((TC) + 1) * 2 + ks) * 512 + lane * 8); \
    }                                                                                    \
    __builtin_amdgcn_s_setprio(1);                                                       \
    {                                                                                    \
      const char* Pl = sm + (PBR) * 8192;                                                \
      _Pragma("unroll")                                                                  \
      for (int ks = 0; ks < 2; ++ks)                                                     \
        _Pragma("unroll")                                                                \
        for (int it = 0; it < 4; ++it) {                                                 \
          int i = it * 16 + l15;                                                         \
          bf16x8 pb = *(const bf16x8*)(Pl + i * 128 +                                    \
                                       (((unsigned)(ks * 64 + g * 16)) ^ ((i & 7) << 4))); \
          _Pragma("unroll")                                                              \
          for (int cs = 0; cs < 4; ++cs)                                                 \
            oc[cs][it] = MFMA16(va[CUR][ks][cs], pb, oc[cs][it]);                        \
        }                                                                                \
    }                                                                                    \
    __builtin_amdgcn_s_setprio(0);                                                       \
    if (DO_S) {                                                                          \
      char* Pw = sm + (PBW) * 8192;                                                      \
      _Pragma("unroll")                                                                  \
      for (int jt = 0; jt < 4; ++jt) {                                                   \
        _Pragma("unroll")                                                                \
        for (int r = 0; r < 4; ++r) {                                                    \
          float p = EXP2(st[jt][r]);                                                     \
          st[jt][r] = p;                                                                 \
          l_run += p;                                                                    \
        }                                                                                \
        unsigned long long u =                                                           \
            ((unsigned long long)pk2(st[jt][2], st[jt][3]) << 32) | pk2(st[jt][0], st[jt][1]); \
        *(unsigned long long*)(Pw + irow * 128 + (((unsigned)(jt * 32 + g * 8)) ^ sw)) = u; \
      }                                                                                  \
    }                                                                                    \
    LDS_BARRIER();                                                                       \
  } while (0)

// ---------------------------------------------------------------------------
// Kernel 3a: attention main loop over a j-HALF. grid 1024; NO occupancy cap
// (R3/R8 lesson: min-waves arg >=4 collapses VGPR budget to 64 and spills;
// at the natural ~108 VGPR the HW itself co-residents 4 blocks/CU).
// Stages unnormalized O^T (bf16, swizzled 32KB image) + l-partials.
// bid = grp*128 + itile*2 + h (XCD-swizzled).
// ---------------------------------------------------------------------------
__global__ __launch_bounds__(256, 2) void attn_main_kernel(short* __restrict__ ws)
{
  const int tid = threadIdx.x, lane = tid & 63, wid = tid >> 6;
  const int g = lane >> 4, l15 = lane & 15;
  const int bid = ((blockIdx.x & 7) << 7) | (blockIdx.x >> 3);
  const int h = bid & 1, itile = (bid >> 1) & 63, grp = bid >> 7;
  const int b = grp & 3, br = grp >> 2;
  const int i0 = itile * 64, t0 = h * 32;

  __shared__ __align__(16) char sm[33024];
  float* l_l = (float*)(sm + 32768);   // 64 floats

  const short* Qb = ws + OFF_QT + (size_t)(br * 4 + b) * (4096 * 32);
  const short* Kb = ws + OFF_KT + (size_t)(br * 4 + b) * (4096 * 32);
  const short* Vb = ws + OFF_V  + (size_t)((1 - br) * 4 + b) * (256 * 4096);

  const f32x4 z4 = {0.f, 0.f, 0.f, 0.f};
  const int irow = wid * 16 + l15;
  const unsigned sw = (unsigned)((irow & 7) << 4);

  bf16x8 qf = *(const bf16x8*)(Qb + (size_t)(i0 + wid * 16 + l15) * 32 + g * 8);

  f32x4 oc[4][4];
#pragma unroll
  for (int i = 0; i < 4; ++i)
#pragma unroll
    for (int j = 0; j < 4; ++j) oc[i][j] = z4;
  float l_run = 0.f;

  // prologue: S(t0) -> P buf0; prefetch kf<-K(t0+1), va<-V(t0)
  {
    bf16x8 kt[4];
#pragma unroll
    for (int jt = 0; jt < 4; ++jt)
      kt[jt] = *(const bf16x8*)(Kb + (size_t)(t0 * 64 + jt * 16 + l15) * 32 + g * 8);
    f32x4 s0[4];
#pragma unroll
    for (int jt = 0; jt < 4; ++jt) s0[jt] = MFMA16(kt[jt], qf, z4);
#pragma unroll
    for (int jt = 0; jt < 4; ++jt) {
#pragma unroll
      for (int r = 0; r < 4; ++r) {
        float p = EXP2(s0[jt][r]);
        s0[jt][r] = p;
        l_run += p;
      }
      unsigned long long u =
          ((unsigned long long)pk2(s0[jt][2], s0[jt][3]) << 32) | pk2(s0[jt][0], s0[jt][1]);
      *(unsigned long long*)(sm + irow * 128 + (((unsigned)(jt * 32 + g * 8)) ^ sw)) = u;
    }
  }

  bf16x8 kf[2][4], va[2][2][4];
#pragma unroll
  for (int jt = 0; jt < 4; ++jt)
    kf[0][jt] = *(const bf16x8*)(Kb + (size_t)((t0 + 1) * 64 + jt * 16 + l15) * 32 + g * 8);
#pragma unroll
  for (int ks = 0; ks < 2; ++ks)
#pragma unroll
    for (int cs = 0; cs < 4; ++cs)
      va[0][ks][cs] = *(const bf16x8*)(Vb + ((size_t)(wid * 4 + cs) * 128 + (size_t)t0 * 2 + ks) * 512 + lane * 8);

  LDS_BARRIER();

  for (int t = t0; t < t0 + 30; t += 2) {
    ATTN_BODY(t, 0, 1, 0, 1, 1, 1, 1);
    ATTN_BODY(t + 1, 1, 0, 1, 0, 1, 1, 1);
  }
  ATTN_BODY(t0 + 30, 0, 1, 0, 1, 1, 0, 1);   // S(t0+31), PV(t0+30), fetch V(t0+31)
  ATTN_BODY(t0 + 31, 1, 0, 1, 0, 0, 0, 0);   // PV(t0+31) only

  // deferred softmax-denominator partial (this half)
  l_run += __shfl_xor(l_run, 16);
  l_run += __shfl_xor(l_run, 32);
  if (g == 0) l_l[irow] = l_run;

  // stage UNNORMALIZED O^T bf16 into the swizzled [i][c] image
#pragma unroll
  for (int cs = 0; cs < 4; ++cs)
#pragma unroll
    for (int it = 0; it < 4; ++it) {
      f32x4 v = oc[cs][it];
      int i = it * 16 + l15;
      unsigned byte = (unsigned)(i * 512) +
                      (((unsigned)((wid * 64 + cs * 16 + g * 4) * 2)) ^ ((i & 7) << 4));
      unsigned long long u = ((unsigned long long)pk2(v[2], v[3]) << 32) | pk2(v[0], v[1]);
      *(unsigned long long*)(sm + byte) = u;
    }
  __syncthreads();

  // coalesced copy of the 32KB image + l partials to workspace
  char* OpH = (char*)(ws + OFF_OP) + (((size_t)(grp * 64 + itile)) * 2 + h) * 32768;
#pragma unroll
  for (int k = 0; k < 8; ++k)
    *(uint4*)(OpH + tid * 128 + k * 16) = *(const uint4*)(sm + tid * 128 + k * 16);
  if (tid < 64) {
    float* Lp = (float*)(ws + OFF_LP);
    Lp[(size_t)(grp * 64 + itile) * 128 + h * 64 + tid] = l_l[tid];
  }
}

// ---------------------------------------------------------------------------
// Kernel 3b: combine partials -> normalize -> Wc GEMM + abs-sum.
// grid 512: bid = grp*64 + itile (XCD-swizzled)
// ---------------------------------------------------------------------------
__global__ __launch_bounds__(256, 2) void combine_kernel(
    short* __restrict__ ws, const float* __restrict__ bc, float* __restrict__ out)
{
  const int tid = threadIdx.x, lane = tid & 63, wid = tid >> 6;
  const int g = lane >> 4, l15 = lane & 15;
  const int bid = ((blockIdx.x & 7) << 6) | (blockIdx.x >> 3);
  const int itile = bid & 63, grp = bid >> 6;
  const int b = grp & 3, br = grp >> 2;
  const int i0 = itile * 64;

  __shared__ __align__(16) char sm[34304];
  float* l_l  = (float*)(sm + 32768);   // 128 floats: l0[64], l1[64]
  float* part = (float*)(sm + 33280);   // 256 floats

  const short* xb  = ws + OFF_XT + (size_t)b * (4096 * 256);   // x1 for both branches
  const short* Wcb = ws + OFF_WC;
  const char*  op0 = (const char*)(ws + OFF_OP) + ((size_t)(grp * 64 + itile) * 2) * 32768;
  const char*  op1 = op0 + 32768;
  const float* Lp  = (const float*)(ws + OFF_LP) + (size_t)(grp * 64 + itile) * 128;

  if (tid < 128) l_l[tid] = Lp[tid];
  __syncthreads();

  // sum halves + normalize, rebuild the swizzled staging image
#pragma unroll
  for (int k = 0; k < 8; ++k) {
    int addr = tid * 128 + k * 16;
    uint4 a  = *(const uint4*)(op0 + addr);
    uint4 b2 = *(const uint4*)(op1 + addr);
    int i = addr >> 9;
    float rl = 1.f / (l_l[i] + l_l[64 + i]);
    uint4 o;
    o.x = addscale2(a.x, b2.x, rl);
    o.y = addscale2(a.y, b2.y, rl);
    o.z = addscale2(a.z, b2.z, rl);
    o.w = addscale2(a.w, b2.w, rl);
    *(uint4*)(sm + addr) = o;
  }
  __syncthreads();

  const f32x4 z4 = {0.f, 0.f, 0.f, 0.f};
  f32x4 cc[4][4];
#pragma unroll
  for (int i = 0; i < 4; ++i)
#pragma unroll
    for (int j = 0; j < 4; ++j) cc[i][j] = z4;

#pragma unroll
  for (int ks = 0; ks < 16; ++ks) {
    bf16x8 bfr[4];
#pragma unroll
    for (int ns = 0; ns < 4; ++ns) {
      int n = ns * 16 + l15;
      if (ks < 8)
        bfr[ns] = *(const bf16x8*)(xb + (size_t)(i0 + n) * 256 + ks * 32 + g * 8);
      else
        bfr[ns] = *(const bf16x8*)(sm + n * 512 +
                                   (((unsigned)((ks - 8) * 64 + g * 16)) ^ ((n & 7) << 4)));
    }
#pragma unroll
    for (int os = 0; os < 4; ++os) {
      bf16x8 af = *(const bf16x8*)(Wcb + (size_t)(wid * 64 + os * 16 + l15) * 512 + ks * 32 + g * 8);
#pragma unroll
      for (int ns = 0; ns < 4; ++ns)
        cc[os][ns] = MFMA16(af, bfr[ns], cc[os][ns]);
    }
  }
  float bcv[4][4];
#pragma unroll
  for (int os = 0; os < 4; ++os)
#pragma unroll
    for (int r = 0; r < 4; ++r) bcv[os][r] = bc[wid * 64 + os * 16 + g * 4 + r];

#pragma unroll
  for (int ns = 0; ns < 4; ++ns) {
    float tsum = 0.f;
#pragma unroll
    for (int os = 0; os < 4; ++os)
#pragma unroll
      for (int r = 0; r < 4; ++r)
        tsum += fabsf(cc[os][ns][r] + bcv[os][r]);
    tsum += __shfl_xor(tsum, 16);
    tsum += __shfl_xor(tsum, 32);
    if (g == 0) part[wid * 64 + ns * 16 + l15] = tsum;
  }
  __syncthreads();
  if (tid < 64) {
    float s = part[tid] + part[64 + tid] + part[128 + tid] + part[192 + tid];
    out[(size_t)br * 16384 + b * 4096 + i0 + tid] = s;
  }
}

// ---------------------------------------------------------------------------
// Kernel 3 (fallback, round-7 fused version): used when ws is too small
// ---------------------------------------------------------------------------
__global__ __launch_bounds__(256, 2) void attn_kernel(
    short* __restrict__ ws, const float* __restrict__ bc, float* __restrict__ out)
{
  const int tid = threadIdx.x, lane = tid & 63, wid = tid >> 6;
  const int g = lane >> 4, l15 = lane & 15;
  const int bid = ((blockIdx.x & 7) << 6) | (blockIdx.x >> 3);
  const int itile = bid & 63, b = (bid >> 6) & 3, br = bid >> 8;
  const int i0 = itile * 64;

  __shared__ __align__(16) char sm[34048];
  float* l_l  = (float*)(sm + 32768);   // 64 floats
  float* part = (float*)(sm + 33024);   // 256 floats

  const short* Qb  = ws + OFF_QT + (size_t)(br * 4 + b) * (4096 * 32);
  const short* Kb  = ws + OFF_KT + (size_t)(br * 4 + b) * (4096 * 32);
  const short* Vb  = ws + OFF_V  + (size_t)((1 - br) * 4 + b) * (256 * 4096);
  const short* xb  = ws + OFF_XT + (size_t)b * (4096 * 256);
  const short* Wcb = ws + OFF_WC;

  const f32x4 z4 = {0.f, 0.f, 0.f, 0.f};
  const int irow = wid * 16 + l15;
  const unsigned sw = (unsigned)((irow & 7) << 4);

  bf16x8 qf = *(const bf16x8*)(Qb + (size_t)(i0 + wid * 16 + l15) * 32 + g * 8);

  f32x4 oc[4][4];
#pragma unroll
  for (int i = 0; i < 4; ++i)
#pragma unroll
    for (int j = 0; j < 4; ++j) oc[i][j] = z4;
  float l_run = 0.f;

  {
    bf16x8 kt[4];
#pragma unroll
    for (int jt = 0; jt < 4; ++jt)
      kt[jt] = *(const bf16x8*)(Kb + (size_t)(jt * 16 + l15) * 32 + g * 8);
    f32x4 s0[4];
#pragma unroll
    for (int jt = 0; jt < 4; ++jt) s0[jt] = MFMA16(kt[jt], qf, z4);
#pragma unroll
    for (int jt = 0; jt < 4; ++jt) {
#pragma unroll
      for (int r = 0; r < 4; ++r) {
        float p = EXP2(s0[jt][r]);
        s0[jt][r] = p;
        l_run += p;
      }
      unsigned long long u =
          ((unsigned long long)pk2(s0[jt][2], s0[jt][3]) << 32) | pk2(s0[jt][0], s0[jt][1]);
      *(unsigned long long*)(sm + irow * 128 + (((unsigned)(jt * 32 + g * 8)) ^ sw)) = u;
    }
  }

  bf16x8 kf[2][4], va[2][2][4];
#pragma unroll
  for (int jt = 0; jt < 4; ++jt)
    kf[0][jt] = *(const bf16x8*)(Kb + (size_t)(64 + jt * 16 + l15) * 32 + g * 8);
#pragma unroll
  for (int ks = 0; ks < 2; ++ks)
#pragma unroll
    for (int cs = 0; cs < 4; ++cs)
      va[0][ks][cs] = *(const bf16x8*)(Vb + ((size_t)(wid * 4 + cs) * 128 + ks) * 512 + lane * 8);

  LDS_BARRIER();

  for (int t = 0; t < 62; t += 2) {
    ATTN_BODY(t, 0, 1, 0, 1, 1, 1, 1);
    ATTN_BODY(t + 1, 1, 0, 1, 0, 1, 1, 1);
  }
  ATTN_BODY(62, 0, 1, 0, 1, 1, 0, 1);
  ATTN_BODY(63, 1, 0, 1, 0, 0, 0, 0);

  l_run += __shfl_xor(l_run, 16);
  l_run += __shfl_xor(l_run, 32);

  if (g == 0) l_l[irow] = l_run;
  __syncthreads();
  float rl[4];
#pragma unroll
  for (int it = 0; it < 4; ++it) rl[it] = 1.f / l_l[it * 16 + l15];

#pragma unroll
  for (int cs = 0; cs < 4; ++cs)
#pragma unroll
    for (int it = 0; it < 4; ++it) {
      f32x4 v = oc[cs][it];
      v *= rl[it];
      int i = it * 16 + l15;
      unsigned byte = (unsigned)(i * 512) +
                      (((unsigned)((wid * 64 + cs * 16 + g * 4) * 2)) ^ ((i & 7) << 4));
      unsigned long long u = ((unsigned long long)pk2(v[2], v[3]) << 32) | pk2(v[0], v[1]);
      *(unsigned long long*)(sm + byte) = u;
    }
  __syncthreads();

  f32x4 cc[4][4];
#pragma unroll
  for (int i = 0; i < 4; ++i)
#pragma unroll
    for (int j = 0; j < 4; ++j) cc[i][j] = z4;

#pragma unroll
  for (int ks = 0; ks < 16; ++ks) {
    bf16x8 bfr[4];
#pragma unroll
    for (int ns = 0; ns < 4; ++ns) {
      int n = ns * 16 + l15;
      if (ks < 8)
        bfr[ns] = *(const bf16x8*)(xb + (size_t)(i0 + n) * 256 + ks * 32 + g * 8);
      else
        bfr[ns] = *(const bf16x8*)(sm + n * 512 +
                                   (((unsigned)((ks - 8) * 64 + g * 16)) ^ ((n & 7) << 4)));
    }
#pragma unroll
    for (int os = 0; os < 4; ++os) {
      bf16x8 af = *(const bf16x8*)(Wcb + (size_t)(wid * 64 + os * 16 + l15) * 512 + ks * 32 + g * 8);
#pragma unroll
      for (int ns = 0; ns < 4; ++ns)
        cc[os][ns] = MFMA16(af, bfr[ns], cc[os][ns]);
    }
  }
  float bcv[4][4];
#pragma unroll
  for (int os = 0; os < 4; ++os)
#pragma unroll
    for (int r = 0; r < 4; ++r) bcv[os][r] = bc[wid * 64 + os * 16 + g * 4 + r];

#pragma unroll
  for (int ns = 0; ns < 4; ++ns) {
    float tsum = 0.f;
#pragma unroll
    for (int os = 0; os < 4; ++os)
#pragma unroll
      for (int r = 0; r < 4; ++r)
        tsum += fabsf(cc[os][ns][r] + bcv[os][r]);
    tsum += __shfl_xor(tsum, 16);
    tsum += __shfl_xor(tsum, 32);
    if (g == 0) part[wid * 64 + ns * 16 + l15] = tsum;
  }
  __syncthreads();
  if (tid < 64) {
    float s = part[tid] + part[64 + tid] + part[128 + tid] + part[192 + tid];
    out[(size_t)br * 16384 + b * 4096 + i0 + tid] = s;
  }
}

// ---------------------------------------------------------------------------
extern "C" void kernel_launch(void* const* d_in, const int* in_sizes, int n_in,
                              void* d_out, int out_size, void* d_ws, size_t ws_size,
                              hipStream_t stream) {
  const float* x1 = (const float*)d_in[0];
  const float* x2 = (const float*)d_in[1];
  const float* Wq = (const float*)d_in[2];
  const float* bq = (const float*)d_in[3];
  const float* Wk = (const float*)d_in[4];
  const float* bk = (const float*)d_in[5];
  const float* Wv = (const float*)d_in[6];
  const float* bv = (const float*)d_in[7];
  const float* Wc = (const float*)d_in[8];
  const float* bc = (const float*)d_in[9];
  short* ws = (short*)d_ws;
  float* out = (float*)d_out;

  prep_kernel<<<2100, 256, 0, stream>>>(x1, x2, Wq, Wk, Wv, Wc, ws);
  proj_kernel<<<768, 256, 0, stream>>>(ws, bq, bk, bv);
  if (ws_size >= WS_NEED_BYTES) {
    attn_main_kernel<<<1024, 256, 0, stream>>>(ws);
    combine_kernel<<<512, 256, 0, stream>>>(ws, bc, out);
  } else {
    attn_kernel<<<512, 256, 0, stream>>>(ws, bc, out);
  }
}

// Round 10
// 135.254 us; speedup vs baseline: 7.0675x; 1.1605x over previous
//
#include <hip/hip_runtime.h>
#include <cstdint>

#define LOG2E 1.4426950408889634f

typedef __bf16 bf16x8 __attribute__((ext_vector_type(8)));
typedef float f32x4 __attribute__((ext_vector_type(4)));

#define MFMA16(a,b,c) __builtin_amdgcn_mfma_f32_16x16x32_bf16((a),(b),(c),0,0,0)
#define EXP2(x) __builtin_amdgcn_exp2f(x)

// barrier that orders LDS ops only (no vmcnt drain -> global prefetches stay in flight)
#define LDS_BARRIER() asm volatile("s_waitcnt lgkmcnt(0)\n\ts_barrier" ::: "memory")

// workspace layout (in shorts/bf16 elements)
constexpr size_t OFF_XT = 0;              // [2][4][4096][256]  = 8,388,608
constexpr size_t OFF_QT = 8388608;        // [2][4][4096][32]   = 1,048,576  (pre-scaled by log2e)
constexpr size_t OFF_KT = 9437184;        // [2][4][4096][32]   = 1,048,576
constexpr size_t OFF_V  = 10485760;       // [2][4] fragment-tiled: subtile(c16,j32) -> 1KB lane-linear
constexpr size_t OFF_WQ = 18874368;       // 32*256
constexpr size_t OFF_WK = 18882560;       // 32*256
constexpr size_t OFF_WV = 18890752;       // 256*256
constexpr size_t OFF_WC = 18956288;       // 256*512

static __device__ __forceinline__ unsigned short f2b(float a) {
  return __builtin_bit_cast(unsigned short, (__bf16)a);
}
static __device__ __forceinline__ unsigned pk2(float a, float b) {
  return ((unsigned)f2b(b) << 16) | (unsigned)f2b(a);
}

// ---------------------------------------------------------------------------
// Kernel 1: transpose-convert x -> xT[n][c] bf16, and convert weights to bf16
// ---------------------------------------------------------------------------
__global__ __launch_bounds__(256) void prep_kernel(
    const float* __restrict__ x1, const float* __restrict__ x2,
    const float* __restrict__ Wq, const float* __restrict__ Wk,
    const float* __restrict__ Wv, const float* __restrict__ Wc,
    short* __restrict__ ws)
{
  __shared__ float tile[64][65];
  const int tid = threadIdx.x;
  const int blk = blockIdx.x;
  if (blk < 2048) {
    const int nt = blk & 63, ct = (blk >> 6) & 3, b = (blk >> 8) & 3, inp = blk >> 10;
    const float* x = (inp ? x2 : x1) + (size_t)(b * 256 + ct * 64) * 4096 + nt * 64;
#pragma unroll
    for (int p = 0; p < 4; ++p) {
      int r = p * 16 + (tid >> 4);
      float4 v = *(const float4*)(x + (size_t)r * 4096 + (tid & 15) * 4);
      tile[r][(tid & 15) * 4 + 0] = v.x;
      tile[r][(tid & 15) * 4 + 1] = v.y;
      tile[r][(tid & 15) * 4 + 2] = v.z;
      tile[r][(tid & 15) * 4 + 3] = v.w;
    }
    __syncthreads();
    const int n = tid >> 2, c0 = (tid & 3) * 16;
    unsigned u[8];
#pragma unroll
    for (int k = 0; k < 8; ++k)
      u[k] = pk2(tile[c0 + 2 * k][n], tile[c0 + 2 * k + 1][n]);
    short* dst = ws + OFF_XT + (size_t)((inp * 4 + b) * 4096 + nt * 64 + n) * 256 + ct * 64 + c0;
    uint4 s0; s0.x = u[0]; s0.y = u[1]; s0.z = u[2]; s0.w = u[3];
    uint4 s1; s1.x = u[4]; s1.y = u[5]; s1.z = u[6]; s1.w = u[7];
    *(uint4*)(dst) = s0;
    *(uint4*)(dst + 8) = s1;
  } else {
    // weight conversion: [Wq | Wk | Wv | Wc] flat
    int idx = (blk - 2048) * 4096 + tid * 16;
    const float* src; short* dst; int off;
    if (idx < 8192)        { src = Wq; dst = ws + OFF_WQ; off = idx; }
    else if (idx < 16384)  { src = Wk; dst = ws + OFF_WK; off = idx - 8192; }
    else if (idx < 81920)  { src = Wv; dst = ws + OFF_WV; off = idx - 16384; }
    else                   { src = Wc; dst = ws + OFF_WC; off = idx - 81920; }
#pragma unroll
    for (int j = 0; j < 16; ++j) dst[off + j] = (short)f2b(src[off + j]);
  }
}

// ---------------------------------------------------------------------------
// Kernel 2 (merged): blk<256 -> Q/K projections; blk>=256 -> V projection.
// ---------------------------------------------------------------------------
static __device__ __forceinline__ void proj_qk_body(
    short* __restrict__ ws, const float* __restrict__ bq, const float* __restrict__ bk,
    int blk, int tid)
{
  const int lane = tid & 63, wid = tid >> 6;
  const int g = lane >> 4, l15 = lane & 15;
  const int nt = blk & 31, b = (blk >> 5) & 3, inp = blk >> 7;
  const int n0 = nt * 128 + wid * 32;

  const short* xp  = ws + OFF_XT + (size_t)(inp * 4 + b) * (4096 * 256) + (size_t)n0 * 256;
  const short* wqp = ws + OFF_WQ;
  const short* wkp = ws + OFF_WK;
  short* Qt = ws + OFF_QT + (size_t)(inp * 4 + b) * (4096 * 32);
  short* Kt = ws + OFF_KT + (size_t)(inp * 4 + b) * (4096 * 32);

  const f32x4 z4 = {0.f, 0.f, 0.f, 0.f};
  f32x4 aq[2][2], ak[2][2];
#pragma unroll
  for (int i = 0; i < 2; ++i)
#pragma unroll
    for (int j = 0; j < 2; ++j) { aq[i][j] = z4; ak[i][j] = z4; }

#pragma unroll
  for (int ks = 0; ks < 8; ++ks) {
    bf16x8 xa[2];
#pragma unroll
    for (int ns = 0; ns < 2; ++ns)
      xa[ns] = *(const bf16x8*)(xp + (size_t)(ns * 16 + l15) * 256 + ks * 32 + g * 8);
#pragma unroll
    for (int os = 0; os < 2; ++os) {
      bf16x8 wq8 = *(const bf16x8*)(wqp + (size_t)(os * 16 + l15) * 256 + ks * 32 + g * 8);
      bf16x8 wk8 = *(const bf16x8*)(wkp + (size_t)(os * 16 + l15) * 256 + ks * 32 + g * 8);
#pragma unroll
      for (int ns = 0; ns < 2; ++ns) {
        aq[ns][os] = MFMA16(xa[ns], wq8, aq[ns][os]);
        ak[ns][os] = MFMA16(xa[ns], wk8, ak[ns][os]);
      }
    }
  }
  float bqv[2], bkv[2];
#pragma unroll
  for (int os = 0; os < 2; ++os) { bqv[os] = bq[os * 16 + l15]; bkv[os] = bk[os * 16 + l15]; }
#pragma unroll
  for (int ns = 0; ns < 2; ++ns)
#pragma unroll
    for (int os = 0; os < 2; ++os)
#pragma unroll
      for (int r = 0; r < 4; ++r) {
        int n = n0 + ns * 16 + g * 4 + r;
        int o = os * 16 + l15;
        Qt[(size_t)n * 32 + o] = (short)f2b((aq[ns][os][r] + bqv[os]) * LOG2E);
        Kt[(size_t)n * 32 + o] = (short)f2b(ak[ns][os][r] + bkv[os]);
      }
}

static __device__ __forceinline__ void proj_v_body(
    short* __restrict__ ws, const float* __restrict__ bv, char* vl, int blk, int tid)
{
  const int lane = tid & 63, wid = tid >> 6;
  const int g = lane >> 4, l15 = lane & 15;
  const int nt = blk & 63, b = (blk >> 6) & 3, inp = blk >> 8;
  const int n0 = nt * 64;

  const short* xp  = ws + OFF_XT + (size_t)(inp * 4 + b) * (4096 * 256) + (size_t)n0 * 256;
  const short* wvp = ws + OFF_WV;
  short* Vp = ws + OFF_V + (size_t)(inp * 4 + b) * (256 * 4096);

  const f32x4 z4 = {0.f, 0.f, 0.f, 0.f};
  f32x4 acc[4][4];
#pragma unroll
  for (int i = 0; i < 4; ++i)
#pragma unroll
    for (int j = 0; j < 4; ++j) acc[i][j] = z4;

#pragma unroll
  for (int ks = 0; ks < 8; ++ks) {
    bf16x8 xa[4];
#pragma unroll
    for (int ns = 0; ns < 4; ++ns)
      xa[ns] = *(const bf16x8*)(xp + (size_t)(ns * 16 + l15) * 256 + ks * 32 + g * 8);
#pragma unroll
    for (int os = 0; os < 4; ++os) {
      bf16x8 wv8 = *(const bf16x8*)(wvp + (size_t)(wid * 64 + os * 16 + l15) * 256 + ks * 32 + g * 8);
#pragma unroll
      for (int ns = 0; ns < 4; ++ns)
        acc[os][ns] = MFMA16(wv8, xa[ns], acc[os][ns]);
    }
  }
  float bvv[4][4];
#pragma unroll
  for (int os = 0; os < 4; ++os)
#pragma unroll
    for (int r = 0; r < 4; ++r) bvv[os][r] = bv[wid * 64 + os * 16 + g * 4 + r];

  char* myl = vl + wid * 8192;
#pragma unroll
  for (int os = 0; os < 4; ++os)
#pragma unroll
    for (int ns = 0; ns < 4; ++ns)
#pragma unroll
      for (int r = 0; r < 4; ++r) {
        int o_loc = os * 16 + g * 4 + r;
        int n_loc = ns * 16 + l15;
        *(short*)(myl + o_loc * 128 + ((n_loc * 2) ^ ((o_loc & 7) << 4))) =
            (short)f2b(acc[os][ns][r] + bvv[os][r]);
      }
  // wave-local fragment readback (same wave -> lgkmcnt ordering suffices)
#pragma unroll
  for (int sc = 0; sc < 4; ++sc)
#pragma unroll
    for (int sj = 0; sj < 2; ++sj) {
      int c_loc = sc * 16 + l15;
      bf16x8 row = *(const bf16x8*)(myl + c_loc * 128 +
                                    (((unsigned)(sj * 64 + g * 16)) ^ ((c_loc & 7) << 4)));
      size_t c16 = (size_t)(wid * 4 + sc);
      size_t j32 = (size_t)(nt * 2 + sj);
      *(bf16x8*)(Vp + (c16 * 128 + j32) * 512 + lane * 8) = row;
    }
}

__global__ __launch_bounds__(256) void proj_kernel(
    short* __restrict__ ws, const float* __restrict__ bq,
    const float* __restrict__ bk, const float* __restrict__ bv)
{
  __shared__ __align__(16) char vl[32768];
  const int tid = threadIdx.x, blk = blockIdx.x;
  if (blk < 256) proj_qk_body(ws, bq, bk, blk, tid);
  else           proj_v_body(ws, bv, vl, blk - 256, tid);
}

// ---------------------------------------------------------------------------
// Kernel 3: fused flash attention, deep-pipelined:
//   at iter t: read pb[NXT] <- P(t+1) (LDS->reg, 1 iter before use);
//   S(t+2) MFMA; PV(t) from REGISTERS (pb[CUR], va) - no lgkm dependency;
//   reload kf <- K(t+3), va <- V(t+1); exp/pack/write P(t+2); 1 barrier.
//   P(n) lives in buf[n&1]; write-2-ahead keeps both buffers disjoint.
// grid 512: bid = br*256 + b*64 + itile (XCD-swizzled)
// ---------------------------------------------------------------------------
__global__ __launch_bounds__(256, 2) void attn_kernel(
    short* __restrict__ ws, const float* __restrict__ bc, float* __restrict__ out)
{
  const int tid = threadIdx.x, lane = tid & 63, wid = tid >> 6;
  const int g = lane >> 4, l15 = lane & 15;
  const int bid = ((blockIdx.x & 7) << 6) | (blockIdx.x >> 3);
  const int itile = bid & 63, b = (bid >> 6) & 3, br = bid >> 8;
  const int i0 = itile * 64;

  __shared__ __align__(16) char sm[34048];
  // loop: [0,16384) = P double-buffer; epilogue: [0,32768) = attT staging
  float* l_l  = (float*)(sm + 32768);   // 64 floats
  float* part = (float*)(sm + 33024);   // 256 floats

  const short* Qb  = ws + OFF_QT + (size_t)(br * 4 + b) * (4096 * 32);
  const short* Kb  = ws + OFF_KT + (size_t)(br * 4 + b) * (4096 * 32);
  const short* Vb  = ws + OFF_V  + (size_t)((1 - br) * 4 + b) * (256 * 4096);
  const short* xb  = ws + OFF_XT + (size_t)b * (4096 * 256);   // x1 for both branches
  const short* Wcb = ws + OFF_WC;

  const f32x4 z4 = {0.f, 0.f, 0.f, 0.f};
  const int irow = wid * 16 + l15;
  const unsigned sw = (unsigned)((irow & 7) << 4);

  // Q fragment for this wave's 16 i-columns (held all pass)
  bf16x8 qf = *(const bf16x8*)(Qb + (size_t)(i0 + wid * 16 + l15) * 32 + g * 8);

  f32x4 oc[4][4];     // O^T [64c (this wave) x 64i]
#pragma unroll
  for (int i = 0; i < 4; ++i)
#pragma unroll
    for (int j = 0; j < 4; ++j) oc[i][j] = z4;
  float l_run = 0.f;  // per-lane partial; cross-lane reduced once after loop

  // ---- prologue: P(0)->buf0, P(1)->buf1; kf<-K(2); va<-V(0); pb[0]<-P(0) ----
#pragma unroll
  for (int tt = 0; tt < 2; ++tt) {
    bf16x8 kt[4];
#pragma unroll
    for (int jt = 0; jt < 4; ++jt)
      kt[jt] = *(const bf16x8*)(Kb + (size_t)(tt * 64 + jt * 16 + l15) * 32 + g * 8);
    f32x4 s0[4];
#pragma unroll
    for (int jt = 0; jt < 4; ++jt) s0[jt] = MFMA16(kt[jt], qf, z4);
    char* Pw = sm + tt * 8192;
#pragma unroll
    for (int jt = 0; jt < 4; ++jt) {
#pragma unroll
      for (int r = 0; r < 4; ++r) {
        float p = EXP2(s0[jt][r]);
        s0[jt][r] = p;
        l_run += p;
      }
      unsigned long long u =
          ((unsigned long long)pk2(s0[jt][2], s0[jt][3]) << 32) | pk2(s0[jt][0], s0[jt][1]);
      *(unsigned long long*)(Pw + irow * 128 + (((unsigned)(jt * 32 + g * 8)) ^ sw)) = u;
    }
  }

  bf16x8 kf[4], va[2][4], pb[2][2][4];
#pragma unroll
  for (int jt = 0; jt < 4; ++jt)
    kf[jt] = *(const bf16x8*)(Kb + (size_t)(128 + jt * 16 + l15) * 32 + g * 8);
#pragma unroll
  for (int ks = 0; ks < 2; ++ks)
#pragma unroll
    for (int cs = 0; cs < 4; ++cs)
      va[ks][cs] = *(const bf16x8*)(Vb + ((size_t)(wid * 4 + cs) * 128 + ks) * 512 + lane * 8);

  LDS_BARRIER();   // P(0), P(1) visible to all waves

#pragma unroll
  for (int ks = 0; ks < 2; ++ks)
#pragma unroll
    for (int it = 0; it < 4; ++it) {
      int i = it * 16 + l15;
      pb[0][ks][it] = *(const bf16x8*)(sm + i * 128 +
                                       (((unsigned)(ks * 64 + g * 16)) ^ ((i & 7) << 4)));
    }
  LDS_BARRIER();   // all pb reads of buf0 done before iter-0 overwrites buf0

  // body at iter TC: pb[NXT]<-P(TC+1) [DO_PB]; S(TC+2) [DO_S]; kf<-K(TC+3)
  // [PREFK]; PV(TC) (va, pb[CUR], registers only); va<-V(TC+1) [PREFV];
  // exp/pack/write P(TC+2)->buf[TC&1] [DO_S]; barrier.
#define ATTN_BODY(TC, CUR, NXT, DO_S, PREFK, PREFV, DO_PB)                               \
  do {                                                                                   \
    if (DO_PB) {                                                                         \
      const char* Pr = sm + (((TC) + 1) & 1) * 8192;                                     \
      _Pragma("unroll")                                                                  \
      for (int ks = 0; ks < 2; ++ks)                                                     \
        _Pragma("unroll")                                                                \
        for (int it = 0; it < 4; ++it) {                                                 \
          int i = it * 16 + l15;                                                         \
          pb[NXT][ks][it] = *(const bf16x8*)(Pr + i * 128 +                              \
                                (((unsigned)(ks * 64 + g * 16)) ^ ((i & 7) << 4)));      \
        }                                                                                \
    }                                                                                    \
    f32x4 st[4];                                                                         \
    if (DO_S) {                                                                          \
      _Pragma("unroll")                                                                  \
      for (int jt = 0; jt < 4; ++jt) st[jt] = MFMA16(kf[jt], qf, z4);                    \
    }                                                                                    \
    if (PREFK) {                                                                         \
      _Pragma("unroll")                                                                  \
      for (int jt = 0; jt < 4; ++jt)                                                     \
        kf[jt] = *(const bf16x8*)(Kb + (size_t)(((TC) + 3) * 64 + jt * 16 + l15) * 32 + g * 8); \
    }                                                                                    \
    __builtin_amdgcn_s_setprio(1);                                                       \
    _Pragma("unroll")                                                                    \
    for (int ks = 0; ks < 2; ++ks)                                                       \
      _Pragma("unroll")                                                                  \
      for (int it = 0; it < 4; ++it)                                                     \
        _Pragma("unroll")                                                                \
        for (int cs = 0; cs < 4; ++cs)                                                   \
          oc[cs][it] = MFMA16(va[ks][cs], pb[CUR][ks][it], oc[cs][it]);                  \
    __builtin_amdgcn_s_setprio(0);                                                       \
    if (PREFV) {                                                                         \
      _Pragma("unroll")                                                                  \
      for (int ks = 0; ks < 2; ++ks)                                                     \
        _Pragma("unroll")                                                                \
        for (int cs = 0; cs < 4; ++cs)                                                   \
          va[ks][cs] = *(const bf16x8*)(Vb + ((size_t)(wid * 4 + cs) * 128 +             \
                                              (size_t)((TC) + 1) * 2 + ks) * 512 + lane * 8); \
    }                                                                                    \
    if (DO_S) {                                                                          \
      char* Pw = sm + ((TC) & 1) * 8192;                                                 \
      _Pragma("unroll")                                                                  \
      for (int jt = 0; jt < 4; ++jt) {                                                   \
        _Pragma("unroll")                                                                \
        for (int r = 0; r < 4; ++r) {                                                    \
          float p = EXP2(st[jt][r]);                                                     \
          st[jt][r] = p;                                                                 \
          l_run += p;                                                                    \
        }                                                                                \
        unsigned long long u =                                                           \
            ((unsigned long long)pk2(st[jt][2], st[jt][3]) << 32) | pk2(st[jt][0], st[jt][1]); \
        *(unsigned long long*)(Pw + irow * 128 + (((unsigned)(jt * 32 + g * 8)) ^ sw)) = u; \
      }                                                                                  \
    }                                                                                    \
    LDS_BARRIER();                                                                       \
  } while (0)

  for (int t = 0; t < 60; t += 2) {
    ATTN_BODY(t,     0, 1, 1, 1, 1, 1);
    ATTN_BODY(t + 1, 1, 0, 1, 1, 1, 1);
  }
  ATTN_BODY(60, 0, 1, 1, 1, 1, 1);   // S(62), kf<-K(63), PV(60)
  ATTN_BODY(61, 1, 0, 1, 0, 1, 1);   // S(63), PV(61)
  ATTN_BODY(62, 0, 1, 0, 0, 1, 1);   // PV(62), pb<-P(63), va<-V(63)
  ATTN_BODY(63, 1, 0, 0, 0, 0, 0);   // PV(63)
#undef ATTN_BODY

  // deferred softmax-denominator reduction (linear, so once is exact)
  l_run += __shfl_xor(l_run, 16);
  l_run += __shfl_xor(l_run, 32);

  // ---- epilogue: normalize, stage attT[i][c] into LDS ----
  if (g == 0) l_l[irow] = l_run;
  __syncthreads();
  float rl[4];
#pragma unroll
  for (int it = 0; it < 4; ++it) rl[it] = 1.f / l_l[it * 16 + l15];

#pragma unroll
  for (int cs = 0; cs < 4; ++cs)
#pragma unroll
    for (int it = 0; it < 4; ++it) {
      f32x4 v = oc[cs][it];
      v *= rl[it];
      int i = it * 16 + l15;
      unsigned byte = (unsigned)(i * 512) +
                      (((unsigned)((wid * 64 + cs * 16 + g * 4) * 2)) ^ ((i & 7) << 4));
      unsigned long long u = ((unsigned long long)pk2(v[2], v[3]) << 32) | pk2(v[0], v[1]);
      *(unsigned long long*)(sm + byte) = u;
    }
  __syncthreads();

  // ---- combine: comb[o,n] = Wc·[x1; att] + bc ; out[n] = sum_o |comb| ----
  f32x4 cc[4][4];
#pragma unroll
  for (int i = 0; i < 4; ++i)
#pragma unroll
    for (int j = 0; j < 4; ++j) cc[i][j] = z4;

#pragma unroll
  for (int ks = 0; ks < 16; ++ks) {
    bf16x8 bfr[4];
#pragma unroll
    for (int ns = 0; ns < 4; ++ns) {
      int n = ns * 16 + l15;
      if (ks < 8)
        bfr[ns] = *(const bf16x8*)(xb + (size_t)(i0 + n) * 256 + ks * 32 + g * 8);
      else
        bfr[ns] = *(const bf16x8*)(sm + n * 512 +
                                   (((unsigned)((ks - 8) * 64 + g * 16)) ^ ((n & 7) << 4)));
    }
#pragma unroll
    for (int os = 0; os < 4; ++os) {
      bf16x8 af = *(const bf16x8*)(Wcb + (size_t)(wid * 64 + os * 16 + l15) * 512 + ks * 32 + g * 8);
#pragma unroll
      for (int ns = 0; ns < 4; ++ns)
        cc[os][ns] = MFMA16(af, bfr[ns], cc[os][ns]);
    }
  }
  float bcv[4][4];
#pragma unroll
  for (int os = 0; os < 4; ++os)
#pragma unroll
    for (int r = 0; r < 4; ++r) bcv[os][r] = bc[wid * 64 + os * 16 + g * 4 + r];

#pragma unroll
  for (int ns = 0; ns < 4; ++ns) {
    float tsum = 0.f;
#pragma unroll
    for (int os = 0; os < 4; ++os)
#pragma unroll
      for (int r = 0; r < 4; ++r)
        tsum += fabsf(cc[os][ns][r] + bcv[os][r]);
    tsum += __shfl_xor(tsum, 16);
    tsum += __shfl_xor(tsum, 32);
    if (g == 0) part[wid * 64 + ns * 16 + l15] = tsum;
  }
  __syncthreads();
  if (tid < 64) {
    float s = part[tid] + part[64 + tid] + part[128 + tid] + part[192 + tid];
    out[(size_t)br * 16384 + b * 4096 + i0 + tid] = s;
  }
}

// ---------------------------------------------------------------------------
extern "C" void kernel_launch(void* const* d_in, const int* in_sizes, int n_in,
                              void* d_out, int out_size, void* d_ws, size_t ws_size,
                              hipStream_t stream) {
  const float* x1 = (const float*)d_in[0];
  const float* x2 = (const float*)d_in[1];
  const float* Wq = (const float*)d_in[2];
  const float* bq = (const float*)d_in[3];
  const float* Wk = (const float*)d_in[4];
  const float* bk = (const float*)d_in[5];
  const float* Wv = (const float*)d_in[6];
  const float* bv = (const float*)d_in[7];
  const float* Wc = (const float*)d_in[8];
  const float* bc = (const float*)d_in[9];
  short* ws = (short*)d_ws;
  float* out = (float*)d_out;

  prep_kernel<<<2100, 256, 0, stream>>>(x1, x2, Wq, Wk, Wv, Wc, ws);
  proj_kernel<<<768, 256, 0, stream>>>(ws, bq, bk, bv);
  attn_kernel<<<512, 256, 0, stream>>>(ws, bc, out);
}

// Round 11
// 134.891 us; speedup vs baseline: 7.0865x; 1.0027x over previous
//
#include <hip/hip_runtime.h>
#include <cstdint>

#define LOG2E 1.4426950408889634f

typedef __bf16 bf16x8 __attribute__((ext_vector_type(8)));
typedef float f32x4 __attribute__((ext_vector_type(4)));

#define MFMA16(a,b,c) __builtin_amdgcn_mfma_f32_16x16x32_bf16((a),(b),(c),0,0,0)
#define EXP2(x) __builtin_amdgcn_exp2f(x)

// barrier that orders LDS ops only (no vmcnt drain -> global prefetches stay in flight)
#define LDS_BARRIER() asm volatile("s_waitcnt lgkmcnt(0)\n\ts_barrier" ::: "memory")

// workspace layout (in shorts/bf16 elements)
constexpr size_t OFF_XT = 0;              // [2][4][4096][256]  = 8,388,608
constexpr size_t OFF_QT = 8388608;        // [2][4][4096][32]   = 1,048,576  (pre-scaled by log2e)
constexpr size_t OFF_KT = 9437184;        // [2][4][4096][32]   = 1,048,576
constexpr size_t OFF_V  = 10485760;       // [2][4] fragment-tiled: subtile(c16,j32) -> 1KB lane-linear
constexpr size_t OFF_WQ = 18874368;       // 32*256
constexpr size_t OFF_WK = 18882560;       // 32*256
constexpr size_t OFF_WV = 18890752;       // 256*256
constexpr size_t OFF_WC = 18956288;       // 256*512

static __device__ __forceinline__ unsigned short f2b(float a) {
  return __builtin_bit_cast(unsigned short, (__bf16)a);
}
static __device__ __forceinline__ unsigned pk2(float a, float b) {
  return ((unsigned)f2b(b) << 16) | (unsigned)f2b(a);
}

// ---------------------------------------------------------------------------
// Kernel 1: transpose-convert x -> xT[n][c] bf16, and convert weights to bf16
// ---------------------------------------------------------------------------
__global__ __launch_bounds__(256) void prep_kernel(
    const float* __restrict__ x1, const float* __restrict__ x2,
    const float* __restrict__ Wq, const float* __restrict__ Wk,
    const float* __restrict__ Wv, const float* __restrict__ Wc,
    short* __restrict__ ws)
{
  __shared__ float tile[64][65];
  const int tid = threadIdx.x;
  const int blk = blockIdx.x;
  if (blk < 2048) {
    const int nt = blk & 63, ct = (blk >> 6) & 3, b = (blk >> 8) & 3, inp = blk >> 10;
    const float* x = (inp ? x2 : x1) + (size_t)(b * 256 + ct * 64) * 4096 + nt * 64;
#pragma unroll
    for (int p = 0; p < 4; ++p) {
      int r = p * 16 + (tid >> 4);
      float4 v = *(const float4*)(x + (size_t)r * 4096 + (tid & 15) * 4);
      tile[r][(tid & 15) * 4 + 0] = v.x;
      tile[r][(tid & 15) * 4 + 1] = v.y;
      tile[r][(tid & 15) * 4 + 2] = v.z;
      tile[r][(tid & 15) * 4 + 3] = v.w;
    }
    __syncthreads();
    const int n = tid >> 2, c0 = (tid & 3) * 16;
    unsigned u[8];
#pragma unroll
    for (int k = 0; k < 8; ++k)
      u[k] = pk2(tile[c0 + 2 * k][n], tile[c0 + 2 * k + 1][n]);
    short* dst = ws + OFF_XT + (size_t)((inp * 4 + b) * 4096 + nt * 64 + n) * 256 + ct * 64 + c0;
    uint4 s0; s0.x = u[0]; s0.y = u[1]; s0.z = u[2]; s0.w = u[3];
    uint4 s1; s1.x = u[4]; s1.y = u[5]; s1.z = u[6]; s1.w = u[7];
    *(uint4*)(dst) = s0;
    *(uint4*)(dst + 8) = s1;
  } else {
    // weight conversion: [Wq | Wk | Wv | Wc] flat
    int idx = (blk - 2048) * 4096 + tid * 16;
    const float* src; short* dst; int off;
    if (idx < 8192)        { src = Wq; dst = ws + OFF_WQ; off = idx; }
    else if (idx < 16384)  { src = Wk; dst = ws + OFF_WK; off = idx - 8192; }
    else if (idx < 81920)  { src = Wv; dst = ws + OFF_WV; off = idx - 16384; }
    else                   { src = Wc; dst = ws + OFF_WC; off = idx - 81920; }
#pragma unroll
    for (int j = 0; j < 16; ++j) dst[off + j] = (short)f2b(src[off + j]);
  }
}

// ---------------------------------------------------------------------------
// Kernel 2 (merged): blk<256 -> Q/K projections; blk>=256 -> V projection.
// ---------------------------------------------------------------------------
static __device__ __forceinline__ void proj_qk_body(
    short* __restrict__ ws, const float* __restrict__ bq, const float* __restrict__ bk,
    int blk, int tid)
{
  const int lane = tid & 63, wid = tid >> 6;
  const int g = lane >> 4, l15 = lane & 15;
  const int nt = blk & 31, b = (blk >> 5) & 3, inp = blk >> 7;
  const int n0 = nt * 128 + wid * 32;

  const short* xp  = ws + OFF_XT + (size_t)(inp * 4 + b) * (4096 * 256) + (size_t)n0 * 256;
  const short* wqp = ws + OFF_WQ;
  const short* wkp = ws + OFF_WK;
  short* Qt = ws + OFF_QT + (size_t)(inp * 4 + b) * (4096 * 32);
  short* Kt = ws + OFF_KT + (size_t)(inp * 4 + b) * (4096 * 32);

  const f32x4 z4 = {0.f, 0.f, 0.f, 0.f};
  f32x4 aq[2][2], ak[2][2];
#pragma unroll
  for (int i = 0; i < 2; ++i)
#pragma unroll
    for (int j = 0; j < 2; ++j) { aq[i][j] = z4; ak[i][j] = z4; }

#pragma unroll
  for (int ks = 0; ks < 8; ++ks) {
    bf16x8 xa[2];
#pragma unroll
    for (int ns = 0; ns < 2; ++ns)
      xa[ns] = *(const bf16x8*)(xp + (size_t)(ns * 16 + l15) * 256 + ks * 32 + g * 8);
#pragma unroll
    for (int os = 0; os < 2; ++os) {
      bf16x8 wq8 = *(const bf16x8*)(wqp + (size_t)(os * 16 + l15) * 256 + ks * 32 + g * 8);
      bf16x8 wk8 = *(const bf16x8*)(wkp + (size_t)(os * 16 + l15) * 256 + ks * 32 + g * 8);
#pragma unroll
      for (int ns = 0; ns < 2; ++ns) {
        aq[ns][os] = MFMA16(xa[ns], wq8, aq[ns][os]);
        ak[ns][os] = MFMA16(xa[ns], wk8, ak[ns][os]);
      }
    }
  }
  float bqv[2], bkv[2];
#pragma unroll
  for (int os = 0; os < 2; ++os) { bqv[os] = bq[os * 16 + l15]; bkv[os] = bk[os * 16 + l15]; }
#pragma unroll
  for (int ns = 0; ns < 2; ++ns)
#pragma unroll
    for (int os = 0; os < 2; ++os)
#pragma unroll
      for (int r = 0; r < 4; ++r) {
        int n = n0 + ns * 16 + g * 4 + r;
        int o = os * 16 + l15;
        Qt[(size_t)n * 32 + o] = (short)f2b((aq[ns][os][r] + bqv[os]) * LOG2E);
        Kt[(size_t)n * 32 + o] = (short)f2b(ak[ns][os][r] + bkv[os]);
      }
}

static __device__ __forceinline__ void proj_v_body(
    short* __restrict__ ws, const float* __restrict__ bv, char* vl, int blk, int tid)
{
  const int lane = tid & 63, wid = tid >> 6;
  const int g = lane >> 4, l15 = lane & 15;
  const int nt = blk & 63, b = (blk >> 6) & 3, inp = blk >> 8;
  const int n0 = nt * 64;

  const short* xp  = ws + OFF_XT + (size_t)(inp * 4 + b) * (4096 * 256) + (size_t)n0 * 256;
  const short* wvp = ws + OFF_WV;
  short* Vp = ws + OFF_V + (size_t)(inp * 4 + b) * (256 * 4096);

  const f32x4 z4 = {0.f, 0.f, 0.f, 0.f};
  f32x4 acc[4][4];
#pragma unroll
  for (int i = 0; i < 4; ++i)
#pragma unroll
    for (int j = 0; j < 4; ++j) acc[i][j] = z4;

#pragma unroll
  for (int ks = 0; ks < 8; ++ks) {
    bf16x8 xa[4];
#pragma unroll
    for (int ns = 0; ns < 4; ++ns)
      xa[ns] = *(const bf16x8*)(xp + (size_t)(ns * 16 + l15) * 256 + ks * 32 + g * 8);
#pragma unroll
    for (int os = 0; os < 4; ++os) {
      bf16x8 wv8 = *(const bf16x8*)(wvp + (size_t)(wid * 64 + os * 16 + l15) * 256 + ks * 32 + g * 8);
#pragma unroll
      for (int ns = 0; ns < 4; ++ns)
        acc[os][ns] = MFMA16(wv8, xa[ns], acc[os][ns]);
    }
  }
  float bvv[4][4];
#pragma unroll
  for (int os = 0; os < 4; ++os)
#pragma unroll
    for (int r = 0; r < 4; ++r) bvv[os][r] = bv[wid * 64 + os * 16 + g * 4 + r];

  char* myl = vl + wid * 8192;
#pragma unroll
  for (int os = 0; os < 4; ++os)
#pragma unroll
    for (int ns = 0; ns < 4; ++ns)
#pragma unroll
      for (int r = 0; r < 4; ++r) {
        int o_loc = os * 16 + g * 4 + r;
        int n_loc = ns * 16 + l15;
        *(short*)(myl + o_loc * 128 + ((n_loc * 2) ^ ((o_loc & 7) << 4))) =
            (short)f2b(acc[os][ns][r] + bvv[os][r]);
      }
  // wave-local fragment readback (same wave -> lgkmcnt ordering suffices)
#pragma unroll
  for (int sc = 0; sc < 4; ++sc)
#pragma unroll
    for (int sj = 0; sj < 2; ++sj) {
      int c_loc = sc * 16 + l15;
      bf16x8 row = *(const bf16x8*)(myl + c_loc * 128 +
                                    (((unsigned)(sj * 64 + g * 16)) ^ ((c_loc & 7) << 4)));
      size_t c16 = (size_t)(wid * 4 + sc);
      size_t j32 = (size_t)(nt * 2 + sj);
      *(bf16x8*)(Vp + (c16 * 128 + j32) * 512 + lane * 8) = row;
    }
}

__global__ __launch_bounds__(256) void proj_kernel(
    short* __restrict__ ws, const float* __restrict__ bq,
    const float* __restrict__ bk, const float* __restrict__ bv)
{
  __shared__ __align__(16) char vl[32768];
  const int tid = threadIdx.x, blk = blockIdx.x;
  if (blk < 256) proj_qk_body(ws, bq, bk, blk, tid);
  else           proj_v_body(ws, bv, vl, blk - 256, tid);
}

// ---------------------------------------------------------------------------
// Kernel 3: fused flash attention, 4-buffer P pipeline:
//   write-3-ahead (P(t+3) written at iter t, buf (t+3)&3), pb read-1-ahead,
//   PV from registers, BARRIER EVERY 2 ITERATIONS (race-audited: with skew
//   <=2 iters all concurrent buffer touches are distinct mod 4, and every
//   P(n) read (iter n-1) is separated from the P(n+4) overwrite (iter n+1)
//   by the intervening odd-iteration barrier).
// grid 512: bid = br*256 + b*64 + itile (XCD-swizzled)
// ---------------------------------------------------------------------------
__global__ __launch_bounds__(256, 2) void attn_kernel(
    short* __restrict__ ws, const float* __restrict__ bc, float* __restrict__ out)
{
  const int tid = threadIdx.x, lane = tid & 63, wid = tid >> 6;
  const int g = lane >> 4, l15 = lane & 15;
  const int bid = ((blockIdx.x & 7) << 6) | (blockIdx.x >> 3);
  const int itile = bid & 63, b = (bid >> 6) & 3, br = bid >> 8;
  const int i0 = itile * 64;

  __shared__ __align__(16) char sm[34048];
  // loop: [0,32768) = 4x8KB P ring; epilogue: [0,32768) = attT staging
  float* l_l  = (float*)(sm + 32768);   // 64 floats
  float* part = (float*)(sm + 33024);   // 256 floats

  const short* Qb  = ws + OFF_QT + (size_t)(br * 4 + b) * (4096 * 32);
  const short* Kb  = ws + OFF_KT + (size_t)(br * 4 + b) * (4096 * 32);
  const short* Vb  = ws + OFF_V  + (size_t)((1 - br) * 4 + b) * (256 * 4096);
  const short* xb  = ws + OFF_XT + (size_t)b * (4096 * 256);   // x1 for both branches
  const short* Wcb = ws + OFF_WC;

  const f32x4 z4 = {0.f, 0.f, 0.f, 0.f};
  const int irow = wid * 16 + l15;
  const unsigned sw = (unsigned)((irow & 7) << 4);

  // Q fragment for this wave's 16 i-columns (held all pass)
  bf16x8 qf = *(const bf16x8*)(Qb + (size_t)(i0 + wid * 16 + l15) * 32 + g * 8);

  f32x4 oc[4][4];     // O^T [64c (this wave) x 64i]
#pragma unroll
  for (int i = 0; i < 4; ++i)
#pragma unroll
    for (int j = 0; j < 4; ++j) oc[i][j] = z4;
  float l_run = 0.f;  // per-lane partial; cross-lane reduced once after loop

  // ---- prologue: P(0..2) -> buf0..2; kf<-K(3); va<-V(0); pb[0]<-P(0) ----
#pragma unroll
  for (int tt = 0; tt < 3; ++tt) {
    bf16x8 kt[4];
#pragma unroll
    for (int jt = 0; jt < 4; ++jt)
      kt[jt] = *(const bf16x8*)(Kb + (size_t)(tt * 64 + jt * 16 + l15) * 32 + g * 8);
    f32x4 s0[4];
#pragma unroll
    for (int jt = 0; jt < 4; ++jt) s0[jt] = MFMA16(kt[jt], qf, z4);
    char* Pw = sm + tt * 8192;
#pragma unroll
    for (int jt = 0; jt < 4; ++jt) {
#pragma unroll
      for (int r = 0; r < 4; ++r) {
        float p = EXP2(s0[jt][r]);
        s0[jt][r] = p;
        l_run += p;
      }
      unsigned long long u =
          ((unsigned long long)pk2(s0[jt][2], s0[jt][3]) << 32) | pk2(s0[jt][0], s0[jt][1]);
      *(unsigned long long*)(Pw + irow * 128 + (((unsigned)(jt * 32 + g * 8)) ^ sw)) = u;
    }
  }

  bf16x8 kf[4], va[2][4], pb[2][2][4];
#pragma unroll
  for (int jt = 0; jt < 4; ++jt)
    kf[jt] = *(const bf16x8*)(Kb + (size_t)(192 + jt * 16 + l15) * 32 + g * 8);
#pragma unroll
  for (int ks = 0; ks < 2; ++ks)
#pragma unroll
    for (int cs = 0; cs < 4; ++cs)
      va[ks][cs] = *(const bf16x8*)(Vb + ((size_t)(wid * 4 + cs) * 128 + ks) * 512 + lane * 8);

  LDS_BARRIER();   // P(0..2) visible to all waves

#pragma unroll
  for (int ks = 0; ks < 2; ++ks)
#pragma unroll
    for (int it = 0; it < 4; ++it) {
      int i = it * 16 + l15;
      pb[0][ks][it] = *(const bf16x8*)(sm + i * 128 +
                                       (((unsigned)(ks * 64 + g * 16)) ^ ((i & 7) << 4)));
    }
  LDS_BARRIER();   // all pb(0) reads done before iter-1 overwrites buf0 (P(4))

  // body at iter TC: pb[NXT]<-P(TC+1) [DO_PB]; S (kf=K(TC+3)) [DO_S];
  // kf<-K(TC+4) [PREFK]; PV(TC) (va, pb[CUR], registers only);
  // va<-V(TC+1) [PREFV]; exp/pack/write P(TC+3)->buf[(TC+3)&3] [DO_S];
  // barrier only when DO_BAR (after odd iters).
#define ATTN_BODY(TC, CUR, NXT, DO_S, PREFK, PREFV, DO_PB, DO_BAR)                       \
  do {                                                                                   \
    if (DO_PB) {                                                                         \
      const char* Pr = sm + (((TC) + 1) & 3) * 8192;                                     \
      _Pragma("unroll")                                                                  \
      for (int ks = 0; ks < 2; ++ks)                                                     \
        _Pragma("unroll")                                                                \
        for (int it = 0; it < 4; ++it) {                                                 \
          int i = it * 16 + l15;                                                         \
          pb[NXT][ks][it] = *(const bf16x8*)(Pr + i * 128 +                              \
                                (((unsigned)(ks * 64 + g * 16)) ^ ((i & 7) << 4)));      \
        }                                                                                \
    }                                                                                    \
    f32x4 st[4];                                                                         \
    if (DO_S) {                                                                          \
      _Pragma("unroll")                                                                  \
      for (int jt = 0; jt < 4; ++jt) st[jt] = MFMA16(kf[jt], qf, z4);                    \
    }                                                                                    \
    if (PREFK) {                                                                         \
      _Pragma("unroll")                                                                  \
      for (int jt = 0; jt < 4; ++jt)                                                     \
        kf[jt] = *(const bf16x8*)(Kb + (size_t)(((TC) + 4) * 64 + jt * 16 + l15) * 32 + g * 8); \
    }                                                                                    \
    __builtin_amdgcn_s_setprio(1);                                                       \
    _Pragma("unroll")                                                                    \
    for (int ks = 0; ks < 2; ++ks)                                                       \
      _Pragma("unroll")                                                                  \
      for (int it = 0; it < 4; ++it)                                                     \
        _Pragma("unroll")                                                                \
        for (int cs = 0; cs < 4; ++cs)                                                   \
          oc[cs][it] = MFMA16(va[ks][cs], pb[CUR][ks][it], oc[cs][it]);                  \
    __builtin_amdgcn_s_setprio(0);                                                       \
    if (PREFV) {                                                                         \
      _Pragma("unroll")                                                                  \
      for (int ks = 0; ks < 2; ++ks)                                                     \
        _Pragma("unroll")                                                                \
        for (int cs = 0; cs < 4; ++cs)                                                   \
          va[ks][cs] = *(const bf16x8*)(Vb + ((size_t)(wid * 4 + cs) * 128 +             \
                                              (size_t)((TC) + 1) * 2 + ks) * 512 + lane * 8); \
    }                                                                                    \
    if (DO_S) {                                                                          \
      char* Pw = sm + (((TC) + 3) & 3) * 8192;                                           \
      _Pragma("unroll")                                                                  \
      for (int jt = 0; jt < 4; ++jt) {                                                   \
        _Pragma("unroll")                                                                \
        for (int r = 0; r < 4; ++r) {                                                    \
          float p = EXP2(st[jt][r]);                                                     \
          st[jt][r] = p;                                                                 \
          l_run += p;                                                                    \
        }                                                                                \
        unsigned long long u =                                                           \
            ((unsigned long long)pk2(st[jt][2], st[jt][3]) << 32) | pk2(st[jt][0], st[jt][1]); \
        *(unsigned long long*)(Pw + irow * 128 + (((unsigned)(jt * 32 + g * 8)) ^ sw)) = u; \
      }                                                                                  \
    }                                                                                    \
    if (DO_BAR) LDS_BARRIER();                                                           \
  } while (0)

  for (int t = 0; t < 60; t += 2) {
    ATTN_BODY(t,     0, 1, 1, 1, 1, 1, 0);
    ATTN_BODY(t + 1, 1, 0, 1, 1, 1, 1, 1);
  }
  // tail: S done at t=60 (P(63)); kf prefetch ended at t=59 (K(63))
  ATTN_BODY(60, 0, 1, 1, 0, 1, 1, 0);   // S->P(63), PV(60), pb<-P(61), va<-V(61)
  ATTN_BODY(61, 1, 0, 0, 0, 1, 1, 1);   // PV(61), pb<-P(62), va<-V(62), barrier
  ATTN_BODY(62, 0, 1, 0, 0, 1, 1, 0);   // PV(62), pb<-P(63), va<-V(63)
  ATTN_BODY(63, 1, 0, 0, 0, 0, 0, 0);   // PV(63)
#undef ATTN_BODY

  // deferred softmax-denominator reduction (linear, so once is exact)
  l_run += __shfl_xor(l_run, 16);
  l_run += __shfl_xor(l_run, 32);

  // ---- epilogue: normalize, stage attT[i][c] into LDS ----
  if (g == 0) l_l[irow] = l_run;
  __syncthreads();
  float rl[4];
#pragma unroll
  for (int it = 0; it < 4; ++it) rl[it] = 1.f / l_l[it * 16 + l15];

#pragma unroll
  for (int cs = 0; cs < 4; ++cs)
#pragma unroll
    for (int it = 0; it < 4; ++it) {
      f32x4 v = oc[cs][it];
      v *= rl[it];
      int i = it * 16 + l15;
      unsigned byte = (unsigned)(i * 512) +
                      (((unsigned)((wid * 64 + cs * 16 + g * 4) * 2)) ^ ((i & 7) << 4));
      unsigned long long u = ((unsigned long long)pk2(v[2], v[3]) << 32) | pk2(v[0], v[1]);
      *(unsigned long long*)(sm + byte) = u;
    }
  __syncthreads();

  // ---- combine: comb[o,n] = Wc·[x1; att] + bc ; out[n] = sum_o |comb| ----
  f32x4 cc[4][4];
#pragma unroll
  for (int i = 0; i < 4; ++i)
#pragma unroll
    for (int j = 0; j < 4; ++j) cc[i][j] = z4;

#pragma unroll
  for (int ks = 0; ks < 16; ++ks) {
    bf16x8 bfr[4];
#pragma unroll
    for (int ns = 0; ns < 4; ++ns) {
      int n = ns * 16 + l15;
      if (ks < 8)
        bfr[ns] = *(const bf16x8*)(xb + (size_t)(i0 + n) * 256 + ks * 32 + g * 8);
      else
        bfr[ns] = *(const bf16x8*)(sm + n * 512 +
                                   (((unsigned)((ks - 8) * 64 + g * 16)) ^ ((n & 7) << 4)));
    }
#pragma unroll
    for (int os = 0; os < 4; ++os) {
      bf16x8 af = *(const bf16x8*)(Wcb + (size_t)(wid * 64 + os * 16 + l15) * 512 + ks * 32 + g * 8);
#pragma unroll
      for (int ns = 0; ns < 4; ++ns)
        cc[os][ns] = MFMA16(af, bfr[ns], cc[os][ns]);
    }
  }
  float bcv[4][4];
#pragma unroll
  for (int os = 0; os < 4; ++os)
#pragma unroll
    for (int r = 0; r < 4; ++r) bcv[os][r] = bc[wid * 64 + os * 16 + g * 4 + r];

#pragma unroll
  for (int ns = 0; ns < 4; ++ns) {
    float tsum = 0.f;
#pragma unroll
    for (int os = 0; os < 4; ++os)
#pragma unroll
      for (int r = 0; r < 4; ++r)
        tsum += fabsf(cc[os][ns][r] + bcv[os][r]);
    tsum += __shfl_xor(tsum, 16);
    tsum += __shfl_xor(tsum, 32);
    if (g == 0) part[wid * 64 + ns * 16 + l15] = tsum;
  }
  __syncthreads();
  if (tid < 64) {
    float s = part[tid] + part[64 + tid] + part[128 + tid] + part[192 + tid];
    out[(size_t)br * 16384 + b * 4096 + i0 + tid] = s;
  }
}

// ---------------------------------------------------------------------------
extern "C" void kernel_launch(void* const* d_in, const int* in_sizes, int n_in,
                              void* d_out, int out_size, void* d_ws, size_t ws_size,
                              hipStream_t stream) {
  const float* x1 = (const float*)d_in[0];
  const float* x2 = (const float*)d_in[1];
  const float* Wq = (const float*)d_in[2];
  const float* bq = (const float*)d_in[3];
  const float* Wk = (const float*)d_in[4];
  const float* bk = (const float*)d_in[5];
  const float* Wv = (const float*)d_in[6];
  const float* bv = (const float*)d_in[7];
  const float* Wc = (const float*)d_in[8];
  const float* bc = (const float*)d_in[9];
  short* ws = (short*)d_ws;
  float* out = (float*)d_out;

  prep_kernel<<<2100, 256, 0, stream>>>(x1, x2, Wq, Wk, Wv, Wc, ws);
  proj_kernel<<<768, 256, 0, stream>>>(ws, bq, bk, bv);
  attn_kernel<<<512, 256, 0, stream>>>(ws, bc, out);
}

// Round 12
// 130.141 us; speedup vs baseline: 7.3452x; 1.0365x over previous
//
#include <hip/hip_runtime.h>
#include <cstdint>

#define LOG2E 1.4426950408889634f

typedef __bf16 bf16x8 __attribute__((ext_vector_type(8)));
typedef float f32x4 __attribute__((ext_vector_type(4)));

#define MFMA16(a,b,c) __builtin_amdgcn_mfma_f32_16x16x32_bf16((a),(b),(c),0,0,0)
#define EXP2(x) __builtin_amdgcn_exp2f(x)

// barrier that orders LDS ops only (no vmcnt drain -> global prefetches stay in flight)
#define LDS_BARRIER() asm volatile("s_waitcnt lgkmcnt(0)\n\ts_barrier" ::: "memory")

// workspace layout (in shorts/bf16 elements)
constexpr size_t OFF_XT = 0;              // [2][4][4096][256]  = 8,388,608
constexpr size_t OFF_QT = 8388608;        // [2][4][4096][32]   = 1,048,576  (pre-scaled by log2e)
constexpr size_t OFF_KT = 9437184;        // [2][4][4096][32]   = 1,048,576
constexpr size_t OFF_V  = 10485760;       // [2][4] fragment-tiled: subtile(c16,j32) -> 1KB lane-linear
constexpr size_t OFF_WQ = 18874368;       // 32*256
constexpr size_t OFF_WK = 18882560;       // 32*256
constexpr size_t OFF_WV = 18890752;       // 256*256
constexpr size_t OFF_WC = 18956288;       // 256*512

static __device__ __forceinline__ unsigned short f2b(float a) {
  return __builtin_bit_cast(unsigned short, (__bf16)a);
}
static __device__ __forceinline__ unsigned pk2(float a, float b) {
  return ((unsigned)f2b(b) << 16) | (unsigned)f2b(a);
}

// ---------------------------------------------------------------------------
// Kernel 1: weight conversion fp32 -> bf16 ([Wq|Wk|Wv|Wc] flat, 52 blocks)
// ---------------------------------------------------------------------------
__global__ __launch_bounds__(256) void weights_kernel(
    const float* __restrict__ Wq, const float* __restrict__ Wk,
    const float* __restrict__ Wv, const float* __restrict__ Wc,
    short* __restrict__ ws)
{
  int idx = blockIdx.x * 4096 + threadIdx.x * 16;
  const float* src; short* dst; int off;
  if (idx < 8192)        { src = Wq; dst = ws + OFF_WQ; off = idx; }
  else if (idx < 16384)  { src = Wk; dst = ws + OFF_WK; off = idx - 8192; }
  else if (idx < 81920)  { src = Wv; dst = ws + OFF_WV; off = idx - 16384; }
  else                   { src = Wc; dst = ws + OFF_WC; off = idx - 81920; }
#pragma unroll
  for (int j = 0; j < 16; ++j) dst[off + j] = (short)f2b(src[off + j]);
}

// ---------------------------------------------------------------------------
// Kernel 2 (fused transpose + Q/K/V projection):
// per block (inp,b,nt64): stage x[256c][64n] fp32 through LDS tile (4 chunks
// of 64c), emit xT to workspace (for attn combine) AND a swizzled bf16
// LDS image xbt[64n][256c]; then QK-project (16n/wave) and V-project
// (64o/wave) reading A-frags from xbt. V epilogue reuses xbt region.
// grid 512: blk = inp*256 + b*64 + nt
// ---------------------------------------------------------------------------
__global__ __launch_bounds__(256) void proj_fused_kernel(
    const float* __restrict__ x1, const float* __restrict__ x2,
    short* __restrict__ ws, const float* __restrict__ bq,
    const float* __restrict__ bk, const float* __restrict__ bv)
{
  __shared__ __align__(16) char smem[49408];   // [0,16640) fp32 tile 64x65 ; [16640,49408) xbt / vl
  float (*tile)[65] = (float(*)[65])smem;
  char* xbt = smem + 16640;

  const int tid = threadIdx.x, lane = tid & 63, wid = tid >> 6;
  const int g = lane >> 4, l15 = lane & 15;
  const int blk = blockIdx.x;
  const int nt = blk & 63, b = (blk >> 6) & 3, inp = blk >> 8;
  const int n0 = nt * 64;

  const float* xsrc = (inp ? x2 : x1) + (size_t)b * 256 * 4096;

  // ---- transpose-convert: 4 chunks of 64 c ----
  const int pn = tid >> 2, pc0 = (tid & 3) * 16;       // pack-phase roles
  const unsigned swn = (unsigned)((pn & 7) << 4);
#pragma unroll
  for (int ct = 0; ct < 4; ++ct) {
#pragma unroll
    for (int p = 0; p < 4; ++p) {
      int r = p * 16 + (tid >> 4);
      float4 v = *(const float4*)(xsrc + (size_t)(ct * 64 + r) * 4096 + n0 + (tid & 15) * 4);
      tile[r][(tid & 15) * 4 + 0] = v.x;
      tile[r][(tid & 15) * 4 + 1] = v.y;
      tile[r][(tid & 15) * 4 + 2] = v.z;
      tile[r][(tid & 15) * 4 + 3] = v.w;
    }
    __syncthreads();
    unsigned u[8];
#pragma unroll
    for (int k = 0; k < 8; ++k)
      u[k] = pk2(tile[pc0 + 2 * k][pn], tile[pc0 + 2 * k + 1][pn]);
    uint4 s0; s0.x = u[0]; s0.y = u[1]; s0.z = u[2]; s0.w = u[3];
    uint4 s1; s1.x = u[4]; s1.y = u[5]; s1.z = u[6]; s1.w = u[7];
    // global xT (combine input)
    short* dst = ws + OFF_XT + (size_t)((inp * 4 + b) * 4096 + n0 + pn) * 256 + ct * 64 + pc0;
    *(uint4*)(dst) = s0;
    *(uint4*)(dst + 8) = s1;
    // LDS xbt, 16B-granular XOR swizzle
    char* row = xbt + pn * 512;
    *(uint4*)(row + (((unsigned)(ct * 128 + pc0 * 2)) ^ swn)) = s0;
    *(uint4*)(row + (((unsigned)(ct * 128 + pc0 * 2 + 16)) ^ swn)) = s1;
    __syncthreads();
  }

  const f32x4 z4 = {0.f, 0.f, 0.f, 0.f};
  // A-fragment loader from xbt: rows of xT (n local), k-chunk = ks*32 + g*8 c's
#define LDX(ROW, KS) (*(const bf16x8*)(xbt + (ROW) * 512 + \
    (((unsigned)((KS) * 64 + g * 16)) ^ ((unsigned)(((ROW) & 7) << 4)))))

  // ---- Q/K projection: wave wid owns 16 n (rows wid*16+l15) ----
  {
    const short* wqp = ws + OFF_WQ;
    const short* wkp = ws + OFF_WK;
    short* Qt = ws + OFF_QT + (size_t)(inp * 4 + b) * (4096 * 32);
    short* Kt = ws + OFF_KT + (size_t)(inp * 4 + b) * (4096 * 32);
    f32x4 aq[2], ak[2];
#pragma unroll
    for (int os = 0; os < 2; ++os) { aq[os] = z4; ak[os] = z4; }
    const int nrow = wid * 16 + l15;
#pragma unroll
    for (int ks = 0; ks < 8; ++ks) {
      bf16x8 xa = LDX(nrow, ks);
#pragma unroll
      for (int os = 0; os < 2; ++os) {
        bf16x8 wq8 = *(const bf16x8*)(wqp + (size_t)(os * 16 + l15) * 256 + ks * 32 + g * 8);
        bf16x8 wk8 = *(const bf16x8*)(wkp + (size_t)(os * 16 + l15) * 256 + ks * 32 + g * 8);
        aq[os] = MFMA16(xa, wq8, aq[os]);
        ak[os] = MFMA16(xa, wk8, ak[os]);
      }
    }
#pragma unroll
    for (int os = 0; os < 2; ++os) {
      float bqv = bq[os * 16 + l15], bkv = bk[os * 16 + l15];
#pragma unroll
      for (int r = 0; r < 4; ++r) {
        int n = n0 + wid * 16 + g * 4 + r;
        int o = os * 16 + l15;
        Qt[(size_t)n * 32 + o] = (short)f2b((aq[os][r] + bqv) * LOG2E);
        Kt[(size_t)n * 32 + o] = (short)f2b(ak[os][r] + bkv);
      }
    }
  }

  // ---- V projection: wave wid owns 64 o; acc[os 4][ns 4] ----
  {
    const short* wvp = ws + OFF_WV;
    short* Vp = ws + OFF_V + (size_t)(inp * 4 + b) * (256 * 4096);
    f32x4 acc[4][4];
#pragma unroll
    for (int i = 0; i < 4; ++i)
#pragma unroll
      for (int j = 0; j < 4; ++j) acc[i][j] = z4;

#pragma unroll
    for (int ks = 0; ks < 8; ++ks) {
      bf16x8 xa[4];
#pragma unroll
      for (int ns = 0; ns < 4; ++ns) xa[ns] = LDX(ns * 16 + l15, ks);
#pragma unroll
      for (int os = 0; os < 4; ++os) {
        bf16x8 wv8 = *(const bf16x8*)(wvp + (size_t)(wid * 64 + os * 16 + l15) * 256 + ks * 32 + g * 8);
#pragma unroll
        for (int ns = 0; ns < 4; ++ns)
          acc[os][ns] = MFMA16(wv8, xa[ns], acc[os][ns]);
      }
    }
    float bvv[4][4];
#pragma unroll
    for (int os = 0; os < 4; ++os)
#pragma unroll
      for (int r = 0; r < 4; ++r) bvv[os][r] = bv[wid * 64 + os * 16 + g * 4 + r];

    __syncthreads();   // all xbt A-frag reads complete before vl overwrite
    char* myl = xbt + wid * 8192;   // V staging reuses xbt region (4 x 8KB)
#pragma unroll
    for (int os = 0; os < 4; ++os)
#pragma unroll
      for (int ns = 0; ns < 4; ++ns)
#pragma unroll
        for (int r = 0; r < 4; ++r) {
          int o_loc = os * 16 + g * 4 + r;
          int n_loc = ns * 16 + l15;
          *(short*)(myl + o_loc * 128 + ((n_loc * 2) ^ ((o_loc & 7) << 4))) =
              (short)f2b(acc[os][ns][r] + bvv[os][r]);
        }
    // wave-local fragment readback (same wave -> lgkmcnt ordering suffices)
#pragma unroll
    for (int sc = 0; sc < 4; ++sc)
#pragma unroll
      for (int sj = 0; sj < 2; ++sj) {
        int c_loc = sc * 16 + l15;
        bf16x8 row = *(const bf16x8*)(myl + c_loc * 128 +
                                      (((unsigned)(sj * 64 + g * 16)) ^ ((c_loc & 7) << 4)));
        size_t c16 = (size_t)(wid * 4 + sc);
        size_t j32 = (size_t)(nt * 2 + sj);
        *(bf16x8*)(Vp + (c16 * 128 + j32) * 512 + lane * 8) = row;
      }
  }
#undef LDX
}

// ---------------------------------------------------------------------------
// Kernel 3: fused flash attention (R10 variant: deep pipeline, pb read-1-ahead,
// P write-2-ahead, 2 buffers, 1 lgkm-barrier/iter, PV from registers).
// grid 512: bid = br*256 + b*64 + itile (XCD-swizzled)
// ---------------------------------------------------------------------------
__global__ __launch_bounds__(256, 2) void attn_kernel(
    short* __restrict__ ws, const float* __restrict__ bc, float* __restrict__ out)
{
  const int tid = threadIdx.x, lane = tid & 63, wid = tid >> 6;
  const int g = lane >> 4, l15 = lane & 15;
  const int bid = ((blockIdx.x & 7) << 6) | (blockIdx.x >> 3);
  const int itile = bid & 63, b = (bid >> 6) & 3, br = bid >> 8;
  const int i0 = itile * 64;

  __shared__ __align__(16) char sm[34048];
  // loop: [0,16384) = P double-buffer; epilogue: [0,32768) = attT staging
  float* l_l  = (float*)(sm + 32768);   // 64 floats
  float* part = (float*)(sm + 33024);   // 256 floats

  const short* Qb  = ws + OFF_QT + (size_t)(br * 4 + b) * (4096 * 32);
  const short* Kb  = ws + OFF_KT + (size_t)(br * 4 + b) * (4096 * 32);
  const short* Vb  = ws + OFF_V  + (size_t)((1 - br) * 4 + b) * (256 * 4096);
  const short* xb  = ws + OFF_XT + (size_t)b * (4096 * 256);   // x1 for both branches
  const short* Wcb = ws + OFF_WC;

  const f32x4 z4 = {0.f, 0.f, 0.f, 0.f};
  const int irow = wid * 16 + l15;
  const unsigned sw = (unsigned)((irow & 7) << 4);

  // Q fragment for this wave's 16 i-columns (held all pass)
  bf16x8 qf = *(const bf16x8*)(Qb + (size_t)(i0 + wid * 16 + l15) * 32 + g * 8);

  f32x4 oc[4][4];     // O^T [64c (this wave) x 64i]
#pragma unroll
  for (int i = 0; i < 4; ++i)
#pragma unroll
    for (int j = 0; j < 4; ++j) oc[i][j] = z4;
  float l_run = 0.f;  // per-lane partial; cross-lane reduced once after loop

  // ---- prologue: P(0)->buf0, P(1)->buf1; kf<-K(2); va<-V(0); pb[0]<-P(0) ----
#pragma unroll
  for (int tt = 0; tt < 2; ++tt) {
    bf16x8 kt[4];
#pragma unroll
    for (int jt = 0; jt < 4; ++jt)
      kt[jt] = *(const bf16x8*)(Kb + (size_t)(tt * 64 + jt * 16 + l15) * 32 + g * 8);
    f32x4 s0[4];
#pragma unroll
    for (int jt = 0; jt < 4; ++jt) s0[jt] = MFMA16(kt[jt], qf, z4);
    char* Pw = sm + tt * 8192;
#pragma unroll
    for (int jt = 0; jt < 4; ++jt) {
#pragma unroll
      for (int r = 0; r < 4; ++r) {
        float p = EXP2(s0[jt][r]);
        s0[jt][r] = p;
        l_run += p;
      }
      unsigned long long u =
          ((unsigned long long)pk2(s0[jt][2], s0[jt][3]) << 32) | pk2(s0[jt][0], s0[jt][1]);
      *(unsigned long long*)(Pw + irow * 128 + (((unsigned)(jt * 32 + g * 8)) ^ sw)) = u;
    }
  }

  bf16x8 kf[4], va[2][4], pb[2][2][4];
#pragma unroll
  for (int jt = 0; jt < 4; ++jt)
    kf[jt] = *(const bf16x8*)(Kb + (size_t)(128 + jt * 16 + l15) * 32 + g * 8);
#pragma unroll
  for (int ks = 0; ks < 2; ++ks)
#pragma unroll
    for (int cs = 0; cs < 4; ++cs)
      va[ks][cs] = *(const bf16x8*)(Vb + ((size_t)(wid * 4 + cs) * 128 + ks) * 512 + lane * 8);

  LDS_BARRIER();   // P(0), P(1) visible to all waves

#pragma unroll
  for (int ks = 0; ks < 2; ++ks)
#pragma unroll
    for (int it = 0; it < 4; ++it) {
      int i = it * 16 + l15;
      pb[0][ks][it] = *(const bf16x8*)(sm + i * 128 +
                                       (((unsigned)(ks * 64 + g * 16)) ^ ((i & 7) << 4)));
    }
  LDS_BARRIER();   // all pb reads of buf0 done before iter-0 overwrites buf0

  // body at iter TC: pb[NXT]<-P(TC+1) [DO_PB]; S(TC+2) [DO_S]; kf<-K(TC+3)
  // [PREFK]; PV(TC) (va, pb[CUR], registers only); va<-V(TC+1) [PREFV];
  // exp/pack/write P(TC+2)->buf[TC&1] [DO_S]; barrier.
#define ATTN_BODY(TC, CUR, NXT, DO_S, PREFK, PREFV, DO_PB)                               \
  do {                                                                                   \
    if (DO_PB) {                                                                         \
      const char* Pr = sm + (((TC) + 1) & 1) * 8192;                                     \
      _Pragma("unroll")                                                                  \
      for (int ks = 0; ks < 2; ++ks)                                                     \
        _Pragma("unroll")                                                                \
        for (int it = 0; it < 4; ++it) {                                                 \
          int i = it * 16 + l15;                                                         \
          pb[NXT][ks][it] = *(const bf16x8*)(Pr + i * 128 +                              \
                                (((unsigned)(ks * 64 + g * 16)) ^ ((i & 7) << 4)));      \
        }                                                                                \
    }                                                                                    \
    f32x4 st[4];                                                                         \
    if (DO_S) {                                                                          \
      _Pragma("unroll")                                                                  \
      for (int jt = 0; jt < 4; ++jt) st[jt] = MFMA16(kf[jt], qf, z4);                    \
    }                                                                                    \
    if (PREFK) {                                                                         \
      _Pragma("unroll")                                                                  \
      for (int jt = 0; jt < 4; ++jt)                                                     \
        kf[jt] = *(const bf16x8*)(Kb + (size_t)(((TC) + 3) * 64 + jt * 16 + l15) * 32 + g * 8); \
    }                                                                                    \
    __builtin_amdgcn_s_setprio(1);                                                       \
    _Pragma("unroll")                                                                    \
    for (int ks = 0; ks < 2; ++ks)                                                       \
      _Pragma("unroll")                                                                  \
      for (int it = 0; it < 4; ++it)                                                     \
        _Pragma("unroll")                                                                \
        for (int cs = 0; cs < 4; ++cs)                                                   \
          oc[cs][it] = MFMA16(va[ks][cs], pb[CUR][ks][it], oc[cs][it]);                  \
    __builtin_amdgcn_s_setprio(0);                                                       \
    if (PREFV) {                                                                         \
      _Pragma("unroll")                                                                  \
      for (int ks = 0; ks < 2; ++ks)                                                     \
        _Pragma("unroll")                                                                \
        for (int cs = 0; cs < 4; ++cs)                                                   \
          va[ks][cs] = *(const bf16x8*)(Vb + ((size_t)(wid * 4 + cs) * 128 +             \
                                              (size_t)((TC) + 1) * 2 + ks) * 512 + lane * 8); \
    }                                                                                    \
    if (DO_S) {                                                                          \
      char* Pw = sm + ((TC) & 1) * 8192;                                                 \
      _Pragma("unroll")                                                                  \
      for (int jt = 0; jt < 4; ++jt) {                                                   \
        _Pragma("unroll")                                                                \
        for (int r = 0; r < 4; ++r) {                                                    \
          float p = EXP2(st[jt][r]);                                                     \
          st[jt][r] = p;                                                                 \
          l_run += p;                                                                    \
        }                                                                                \
        unsigned long long u =                                                           \
            ((unsigned long long)pk2(st[jt][2], st[jt][3]) << 32) | pk2(st[jt][0], st[jt][1]); \
        *(unsigned long long*)(Pw + irow * 128 + (((unsigned)(jt * 32 + g * 8)) ^ sw)) = u; \
      }                                                                                  \
    }                                                                                    \
    LDS_BARRIER();                                                                       \
  } while (0)

  for (int t = 0; t < 60; t += 2) {
    ATTN_BODY(t,     0, 1, 1, 1, 1, 1);
    ATTN_BODY(t + 1, 1, 0, 1, 1, 1, 1);
  }
  ATTN_BODY(60, 0, 1, 1, 1, 1, 1);   // S(62), kf<-K(63), PV(60)
  ATTN_BODY(61, 1, 0, 1, 0, 1, 1);   // S(63), PV(61)
  ATTN_BODY(62, 0, 1, 0, 0, 1, 1);   // PV(62), pb<-P(63), va<-V(63)
  ATTN_BODY(63, 1, 0, 0, 0, 0, 0);   // PV(63)
#undef ATTN_BODY

  // deferred softmax-denominator reduction (linear, so once is exact)
  l_run += __shfl_xor(l_run, 16);
  l_run += __shfl_xor(l_run, 32);

  // ---- epilogue: normalize, stage attT[i][c] into LDS ----
  if (g == 0) l_l[irow] = l_run;
  __syncthreads();
  float rl[4];
#pragma unroll
  for (int it = 0; it < 4; ++it) rl[it] = 1.f / l_l[it * 16 + l15];

#pragma unroll
  for (int cs = 0; cs < 4; ++cs)
#pragma unroll
    for (int it = 0; it < 4; ++it) {
      f32x4 v = oc[cs][it];
      v *= rl[it];
      int i = it * 16 + l15;
      unsigned byte = (unsigned)(i * 512) +
                      (((unsigned)((wid * 64 + cs * 16 + g * 4) * 2)) ^ ((i & 7) << 4));
      unsigned long long u = ((unsigned long long)pk2(v[2], v[3]) << 32) | pk2(v[0], v[1]);
      *(unsigned long long*)(sm + byte) = u;
    }
  __syncthreads();

  // ---- combine: comb[o,n] = Wc·[x1; att] + bc ; out[n] = sum_o |comb| ----
  f32x4 cc[4][4];
#pragma unroll
  for (int i = 0; i < 4; ++i)
#pragma unroll
    for (int j = 0; j < 4; ++j) cc[i][j] = z4;

#pragma unroll
  for (int ks = 0; ks < 16; ++ks) {
    bf16x8 bfr[4];
#pragma unroll
    for (int ns = 0; ns < 4; ++ns) {
      int n = ns * 16 + l15;
      if (ks < 8)
        bfr[ns] = *(const bf16x8*)(xb + (size_t)(i0 + n) * 256 + ks * 32 + g * 8);
      else
        bfr[ns] = *(const bf16x8*)(sm + n * 512 +
                                   (((unsigned)((ks - 8) * 64 + g * 16)) ^ ((n & 7) << 4)));
    }
#pragma unroll
    for (int os = 0; os < 4; ++os) {
      bf16x8 af = *(const bf16x8*)(Wcb + (size_t)(wid * 64 + os * 16 + l15) * 512 + ks * 32 + g * 8);
#pragma unroll
      for (int ns = 0; ns < 4; ++ns)
        cc[os][ns] = MFMA16(af, bfr[ns], cc[os][ns]);
    }
  }
  float bcv[4][4];
#pragma unroll
  for (int os = 0; os < 4; ++os)
#pragma unroll
    for (int r = 0; r < 4; ++r) bcv[os][r] = bc[wid * 64 + os * 16 + g * 4 + r];

#pragma unroll
  for (int ns = 0; ns < 4; ++ns) {
    float tsum = 0.f;
#pragma unroll
    for (int os = 0; os < 4; ++os)
#pragma unroll
      for (int r = 0; r < 4; ++r)
        tsum += fabsf(cc[os][ns][r] + bcv[os][r]);
    tsum += __shfl_xor(tsum, 16);
    tsum += __shfl_xor(tsum, 32);
    if (g == 0) part[wid * 64 + ns * 16 + l15] = tsum;
  }
  __syncthreads();
  if (tid < 64) {
    float s = part[tid] + part[64 + tid] + part[128 + tid] + part[192 + tid];
    out[(size_t)br * 16384 + b * 4096 + i0 + tid] = s;
  }
}

// ---------------------------------------------------------------------------
extern "C" void kernel_launch(void* const* d_in, const int* in_sizes, int n_in,
                              void* d_out, int out_size, void* d_ws, size_t ws_size,
                              hipStream_t stream) {
  const float* x1 = (const float*)d_in[0];
  const float* x2 = (const float*)d_in[1];
  const float* Wq = (const float*)d_in[2];
  const float* bq = (const float*)d_in[3];
  const float* Wk = (const float*)d_in[4];
  const float* bk = (const float*)d_in[5];
  const float* Wv = (const float*)d_in[6];
  const float* bv = (const float*)d_in[7];
  const float* Wc = (const float*)d_in[8];
  const float* bc = (const float*)d_in[9];
  short* ws = (short*)d_ws;
  float* out = (float*)d_out;

  weights_kernel<<<52, 256, 0, stream>>>(Wq, Wk, Wv, Wc, ws);
  proj_fused_kernel<<<512, 256, 0, stream>>>(x1, x2, ws, bq, bk, bv);
  attn_kernel<<<512, 256, 0, stream>>>(ws, bc, out);
}